// Round 1
// baseline (554.585 us; speedup 1.0000x reference)
//
#include <hip/hip_runtime.h>
#include <hip/hip_bf16.h>
#include <hip/hip_cooperative_groups.h>

namespace cg = cooperative_groups;

// ---------------------------------------------------------------------------
// GraphSAGE 3-layer + global mean pool, fp32 in/out.
//   layer: agg = mean_{e:dst=n} relu(h[src_e]);  h' = agg@Wl^T + bl + h@Wr^T
// R1-R14 history: 810 -> 336us (see prior session). Gather at ~27us is the
//   random-gather service floor; GEMMs not staging-bound (R12).
// R15 (this round): structural serialization attack:
//   (a) cooperative front-end: init+deg+scan_p1+scan_p23+fill fused into ONE
//       kernel (3 grid syncs); x-conversion BW overlaps deg-atomic latency.
//   (b) sage_mfma: phases A+B merged into one K-loop (16->8 barriers,
//       40 MFMA per barrier-pair). Same product set, same math.
//   (c) agg40+pool fused: per-block run-length reduce (batch sorted) ->
//       ~1 atomicAdd/block/col into gsum (zeroed in front-end P0).
//   Dispatches 12 -> 7. Predict 336 -> ~305us.
// ---------------------------------------------------------------------------

#define NODES 50000
#define K_DIM 128
#define N_GRAPHS 128

typedef __attribute__((ext_vector_type(8))) short short8;
typedef __attribute__((ext_vector_type(4))) short short4v;
typedef __attribute__((ext_vector_type(4))) float f32x4;

__device__ inline short f2bf(float f) {
    unsigned u = __builtin_bit_cast(unsigned, f);
    u += 0x7FFFu + ((u >> 16) & 1u);          // RNE
    return (short)(u >> 16);
}
__device__ inline float bf2f(short h) {
    unsigned u = ((unsigned)(unsigned short)h) << 16;
    return __builtin_bit_cast(float, u);
}
__device__ inline float blo(unsigned u) { return __builtin_bit_cast(float, u << 16); }
__device__ inline float bhi(unsigned u) { return __builtin_bit_cast(float, u & 0xFFFF0000u); }
// pack: bits[15:0]=hi bf16, bits[31:16]=lo bf16
__device__ inline unsigned hilo_pack(float f) {
    short h = f2bf(f);
    short l = f2bf(f - bf2f(h));
    return ((unsigned)(unsigned short)h) | (((unsigned)(unsigned short)l) << 16);
}

// ---------------------------------------------------------------------------
// Cooperative front-end: P0 zeros+weights+gstart | P1 xconv ∥ deg-atomics |
// P2 one-phase scan -> rowptr/fillpos | P3 CSR fill.
// grid = 512 blocks x 256 (launch_bounds(256,2) => 2 blocks/CU co-resident).
// ---------------------------------------------------------------------------
__global__ __launch_bounds__(256, 2) void frontend(
        const float* __restrict__ w0, const float* __restrict__ w1,
        const float* __restrict__ w2, const float* __restrict__ w3,
        const float* __restrict__ w4, const float* __restrict__ w5,
        short* __restrict__ whi, short* __restrict__ wlo,
        const float* __restrict__ x, short* __restrict__ xb,
        short* __restrict__ xhi, short* __restrict__ xlo,
        const int* __restrict__ batch, int* __restrict__ gstart,
        const int* __restrict__ src, const int* __restrict__ dst,
        int* __restrict__ deg, int* __restrict__ rowptr,
        int* __restrict__ fillpos, int* __restrict__ csr,
        float* __restrict__ gsum,
        int N, int E, int NB) {
    cg::grid_group grid = cg::this_grid();
    const int gs  = gridDim.x * blockDim.x;
    const int id0 = blockIdx.x * blockDim.x + threadIdx.x;

    // ---------------- P0: zero deg + gsum, convert weights, gstart ----------
    for (int i = id0; i < N; i += gs) deg[i] = 0;
    for (int i = id0; i < N_GRAPHS * 40; i += gs) gsum[i] = 0.f;
    for (int i = id0; i < 77824; i += gs) {
        float v;
        if (i < 65536) {
            int m = i >> 14, e2 = i & 16383;
            const float* W = (m == 0) ? w0 : (m == 1) ? w1 : (m == 2) ? w2 : w3;
            v = W[e2];
        } else {
            int i2 = i - 65536;
            int row = i2 >> 7, col = i2 & 127;
            if (row < 40)      v = w4[row * 128 + col];
            else if (row < 80) v = w5[(row - 40) * 128 + col];
            else               v = 0.f;
        }
        unsigned p = hilo_pack(v);
        whi[i] = (short)(p & 0xFFFFu);
        wlo[i] = (short)(p >> 16);
    }
    for (int g = id0; g <= N_GRAPHS; g += gs) {
        int lo = 0, hi2 = N;
        while (lo < hi2) {
            int mid = (lo + hi2) >> 1;
            if (batch[mid] < g) lo = mid + 1; else hi2 = mid;
        }
        gstart[g] = lo;
    }
    grid.sync();

    // ---------------- P1: x -> xb/xhi/xlo  (BW)  ∥  deg atomics (latency) ---
    for (int e = id0; e < E; e += gs) atomicAdd(&deg[dst[e]], 1);
    for (int idx = id0; idx < N * (K_DIM / 4); idx += gs) {
        float4 v = reinterpret_cast<const float4*>(x)[idx];
        unsigned px = hilo_pack(v.x), py = hilo_pack(v.y);
        unsigned pz = hilo_pack(v.z), pw = hilo_pack(v.w);
        short4v b, hh, ll;
        b[0] = f2bf(fmaxf(v.x, 0.f)); hh[0] = (short)(px & 0xFFFFu); ll[0] = (short)(px >> 16);
        b[1] = f2bf(fmaxf(v.y, 0.f)); hh[1] = (short)(py & 0xFFFFu); ll[1] = (short)(py >> 16);
        b[2] = f2bf(fmaxf(v.z, 0.f)); hh[2] = (short)(pz & 0xFFFFu); ll[2] = (short)(pz >> 16);
        b[3] = f2bf(fmaxf(v.w, 0.f)); hh[3] = (short)(pw & 0xFFFFu); ll[3] = (short)(pw >> 16);
        *reinterpret_cast<short4v*>(&xb [idx * 4]) = b;
        *reinterpret_cast<short4v*>(&xhi[idx * 4]) = hh;
        *reinterpret_cast<short4v*>(&xlo[idx * 4]) = ll;
    }
    grid.sync();

    // ---------------- P2: one-phase exclusive scan -> rowptr + fillpos ------
    __shared__ int ws[4];
    __shared__ int ws2[4];
    for (int c = blockIdx.x; c < NB; c += gridDim.x) {
        const int tid = threadIdx.x, lane = tid & 63, wv = tid >> 6;
        const int start = c * 256;
        // base = sum deg[0..start)  (deg is 200KB, L2-resident)
        int part = 0;
        for (int j = tid; j < start; j += 256) part += deg[j];
        #pragma unroll
        for (int off = 32; off > 0; off >>= 1) part += __shfl_down(part, off, 64);
        if (lane == 0) ws[wv] = part;
        __syncthreads();
        const int base = ws[0] + ws[1] + ws[2] + ws[3];
        // local inclusive scan of this 256-chunk
        int i = start + tid;
        int v = (i < N) ? deg[i] : 0;
        int incl = v;
        #pragma unroll
        for (int off = 1; off < 64; off <<= 1) {
            int t = __shfl_up(incl, off, 64);
            if (lane >= off) incl += t;
        }
        if (lane == 63) ws2[wv] = incl;
        __syncthreads();
        int add = 0;
        for (int k = 0; k < wv; ++k) add += ws2[k];
        const int tot = incl + add;
        const int excl = base + tot - v;
        if (i < N) { rowptr[i] = excl; fillpos[i] = excl; }
        if (c == NB - 1 && tid == 255) rowptr[N] = base + tot;
        __syncthreads();
    }
    grid.sync();

    // ---------------- P3: CSR fill ------------------------------------------
    for (int e = id0; e < E; e += gs) {
        int p = atomicAdd(&fillpos[dst[e]], 1);
        csr[p] = src[e];
    }
}

// ------- aggregation from bf16 table (128-dim) -> bf16 mean ----------------
__global__ void agg_bf16(const unsigned short* __restrict__ hb,
                         const int* __restrict__ rowptr,
                         const int* __restrict__ csr_src,
                         short* __restrict__ aggb, int N) {
    int w = (blockIdx.x * blockDim.x + threadIdx.x) >> 6;
    if (w >= N) return;
    int lane = threadIdx.x & 63;
    int half = lane >> 5, l32 = lane & 31;
    int s = rowptr[w], e = rowptr[w + 1];
    float4 acc = make_float4(0.f, 0.f, 0.f, 0.f);
    int i = s + half;
    for (; i + 6 < e; i += 8) {
        int s0 = csr_src[i], s1 = csr_src[i + 2], s2 = csr_src[i + 4], s3 = csr_src[i + 6];
        uint2 v0 = reinterpret_cast<const uint2*>(hb + (size_t)s0 * K_DIM)[l32];
        uint2 v1 = reinterpret_cast<const uint2*>(hb + (size_t)s1 * K_DIM)[l32];
        uint2 v2 = reinterpret_cast<const uint2*>(hb + (size_t)s2 * K_DIM)[l32];
        uint2 v3 = reinterpret_cast<const uint2*>(hb + (size_t)s3 * K_DIM)[l32];
        acc.x += (blo(v0.x) + blo(v1.x)) + (blo(v2.x) + blo(v3.x));
        acc.y += (bhi(v0.x) + bhi(v1.x)) + (bhi(v2.x) + bhi(v3.x));
        acc.z += (blo(v0.y) + blo(v1.y)) + (blo(v2.y) + blo(v3.y));
        acc.w += (bhi(v0.y) + bhi(v1.y)) + (bhi(v2.y) + bhi(v3.y));
    }
    for (; i < e; i += 2) {
        int s0 = csr_src[i];
        uint2 v0 = reinterpret_cast<const uint2*>(hb + (size_t)s0 * K_DIM)[l32];
        acc.x += blo(v0.x); acc.y += bhi(v0.x);
        acc.z += blo(v0.y); acc.w += bhi(v0.y);
    }
    acc.x += __shfl_xor(acc.x, 32, 64);
    acc.y += __shfl_xor(acc.y, 32, 64);
    acc.z += __shfl_xor(acc.z, 32, 64);
    acc.w += __shfl_xor(acc.w, 32, 64);
    if (half == 0) {
        float inv = 1.0f / fmaxf((float)(e - s), 1.0f);
        short4v b;
        b[0] = f2bf(acc.x * inv);
        b[1] = f2bf(acc.y * inv);
        b[2] = f2bf(acc.z * inv);
        b[3] = f2bf(acc.w * inv);
        *reinterpret_cast<short4v*>(&aggb[(size_t)w * K_DIM + l32 * 4]) = b;
    }
}

// --------- MFMA layer GEMM: out = aggb@Wl^T + bl + H@Wr^T, relu ------------
// R15: single merged K-loop (A and B phase tiles staged together):
//   8 barriers instead of 16, 40 MFMAs per barrier-pair.
__global__ __launch_bounds__(256) void sage_mfma(
        const short* __restrict__ Ab_in,
        const short* __restrict__ Hhi_in, const short* __restrict__ Hlo_in,
        const short* __restrict__ Bhl, const short* __restrict__ Bll,
        const short* __restrict__ Bhr, const short* __restrict__ Blr,
        const float* __restrict__ bl,
        short* __restrict__ outHi, short* __restrict__ outLo, int N) {
    constexpr int BM = 64;
    constexpr int LSTR = 40;
    const int tid = threadIdx.x;
    const int lane = tid & 63;
    const int wave = tid >> 6;
    const int l15 = lane & 15;
    const int quad = lane >> 4;
    const int m0 = blockIdx.x * BM;
    const int srow = tid >> 2, sc8 = tid & 3;

    __shared__ __align__(16) short Ab [BM * LSTR];
    __shared__ __align__(16) short Ahi[BM * LSTR];
    __shared__ __align__(16) short Alo[BM * LSTR];

    f32x4 acc[4][2];
    #pragma unroll
    for (int i = 0; i < 4; ++i)
        #pragma unroll
        for (int j = 0; j < 2; ++j) acc[i][j] = (f32x4){0.f, 0.f, 0.f, 0.f};

    const short8 zero8 = (short8){0, 0, 0, 0, 0, 0, 0, 0};
    const int sm = m0 + srow;

    for (int k0 = 0; k0 < K_DIM; k0 += 32) {
        __syncthreads();
        {
            short8 va = zero8, vh = zero8, vl = zero8;
            if (sm < N) {
                va = *reinterpret_cast<const short8*>(Ab_in  + (size_t)sm * K_DIM + k0 + sc8 * 8);
                vh = *reinterpret_cast<const short8*>(Hhi_in + (size_t)sm * K_DIM + k0 + sc8 * 8);
                vl = *reinterpret_cast<const short8*>(Hlo_in + (size_t)sm * K_DIM + k0 + sc8 * 8);
            }
            *reinterpret_cast<short8*>(&Ab [srow * LSTR + sc8 * 8]) = va;
            *reinterpret_cast<short8*>(&Ahi[srow * LSTR + sc8 * 8]) = vh;
            *reinterpret_cast<short8*>(&Alo[srow * LSTR + sc8 * 8]) = vl;
        }
        short8 bhl_[2], bll_[2], bhr_[2], blr_[2];
        #pragma unroll
        for (int nt = 0; nt < 2; ++nt) {
            int n = wave * 32 + nt * 16 + l15;
            size_t off = (size_t)n * K_DIM + k0 + quad * 8;
            bhl_[nt] = *reinterpret_cast<const short8*>(Bhl + off);
            bll_[nt] = *reinterpret_cast<const short8*>(Bll + off);
            bhr_[nt] = *reinterpret_cast<const short8*>(Bhr + off);
            blr_[nt] = *reinterpret_cast<const short8*>(Blr + off);
        }
        __syncthreads();
        #pragma unroll
        for (int mt = 0; mt < 4; ++mt) {
            int row = mt * 16 + l15;
            short8 ab = *reinterpret_cast<const short8*>(&Ab [row * LSTR + quad * 8]);
            short8 ah = *reinterpret_cast<const short8*>(&Ahi[row * LSTR + quad * 8]);
            short8 ao = *reinterpret_cast<const short8*>(&Alo[row * LSTR + quad * 8]);
            #pragma unroll
            for (int nt = 0; nt < 2; ++nt) {
                acc[mt][nt] = __builtin_amdgcn_mfma_f32_16x16x32_bf16(ab, bhl_[nt], acc[mt][nt], 0, 0, 0);
                acc[mt][nt] = __builtin_amdgcn_mfma_f32_16x16x32_bf16(ab, bll_[nt], acc[mt][nt], 0, 0, 0);
                acc[mt][nt] = __builtin_amdgcn_mfma_f32_16x16x32_bf16(ah, bhr_[nt], acc[mt][nt], 0, 0, 0);
                acc[mt][nt] = __builtin_amdgcn_mfma_f32_16x16x32_bf16(ah, blr_[nt], acc[mt][nt], 0, 0, 0);
                acc[mt][nt] = __builtin_amdgcn_mfma_f32_16x16x32_bf16(ao, bhr_[nt], acc[mt][nt], 0, 0, 0);
            }
        }
    }

    // ---- epilogue: relu(acc + bias) -> hi/lo planes ----
    #pragma unroll
    for (int mt = 0; mt < 4; ++mt) {
        #pragma unroll
        for (int nt = 0; nt < 2; ++nt) {
            int col = wave * 32 + nt * 16 + l15;
            float b = bl[col];
            #pragma unroll
            for (int reg = 0; reg < 4; ++reg) {
                int row = m0 + mt * 16 + quad * 4 + reg;
                if (row < N) {
                    float v = fmaxf(acc[mt][nt][reg] + b, 0.f);
                    unsigned p = hilo_pack(v);
                    outHi[(size_t)row * K_DIM + col] = (short)(p & 0xFFFFu);
                    outLo[(size_t)row * K_DIM + col] = (short)(p >> 16);
                }
            }
        }
    }
}

// ------ layer-2 GEMM: ylb = bf16(h2@Wl2^T), yr40 = h2@Wr2^T + bl2 ----------
__global__ __launch_bounds__(256) void gemm80(
        const short* __restrict__ Xhi, const short* __restrict__ Xlo,
        const short* __restrict__ Bh, const short* __restrict__ Bv,
        const float* __restrict__ b2,
        short* __restrict__ ylb, float* __restrict__ yr40, int N) {
    constexpr int BM = 64;
    constexpr int LSTR = 40;
    const int tid = threadIdx.x;
    const int lane = tid & 63;
    const int wave = tid >> 6;
    const int wm = wave & 1;
    const int wn = wave >> 1;
    const int l15 = lane & 15;
    const int quad = lane >> 4;
    const int m0 = blockIdx.x * BM;
    const int srow = tid >> 2, sc8 = tid & 3;

    __shared__ __align__(16) short Ahi[BM * LSTR];
    __shared__ __align__(16) short Alo[BM * LSTR];

    f32x4 acc[2][3];
    #pragma unroll
    for (int i = 0; i < 2; ++i)
        #pragma unroll
        for (int j = 0; j < 3; ++j) acc[i][j] = (f32x4){0.f, 0.f, 0.f, 0.f};

    const short8 zero8 = (short8){0, 0, 0, 0, 0, 0, 0, 0};
    const int sm = m0 + srow;

    for (int k0 = 0; k0 < K_DIM; k0 += 32) {
        __syncthreads();
        {
            short8 vh = zero8, vl = zero8;
            if (sm < N) {
                vh = *reinterpret_cast<const short8*>(Xhi + (size_t)sm * K_DIM + k0 + sc8 * 8);
                vl = *reinterpret_cast<const short8*>(Xlo + (size_t)sm * K_DIM + k0 + sc8 * 8);
            }
            *reinterpret_cast<short8*>(&Ahi[srow * LSTR + sc8 * 8]) = vh;
            *reinterpret_cast<short8*>(&Alo[srow * LSTR + sc8 * 8]) = vl;
        }
        short8 bh[3], bo[3];
        #pragma unroll
        for (int nt = 0; nt < 3; ++nt) {
            int n = wn * 48 + nt * 16 + l15;   // < 96
            bh[nt] = *reinterpret_cast<const short8*>(Bh + (size_t)n * K_DIM + k0 + quad * 8);
            bo[nt] = *reinterpret_cast<const short8*>(Bv + (size_t)n * K_DIM + k0 + quad * 8);
        }
        __syncthreads();
        #pragma unroll
        for (int mt = 0; mt < 2; ++mt) {
            int row = wm * 32 + mt * 16 + l15;
            short8 ah = *reinterpret_cast<const short8*>(&Ahi[row * LSTR + quad * 8]);
            short8 ao = *reinterpret_cast<const short8*>(&Alo[row * LSTR + quad * 8]);
            #pragma unroll
            for (int nt = 0; nt < 3; ++nt) {
                acc[mt][nt] = __builtin_amdgcn_mfma_f32_16x16x32_bf16(ah, bh[nt], acc[mt][nt], 0, 0, 0);
                acc[mt][nt] = __builtin_amdgcn_mfma_f32_16x16x32_bf16(ah, bo[nt], acc[mt][nt], 0, 0, 0);
                acc[mt][nt] = __builtin_amdgcn_mfma_f32_16x16x32_bf16(ao, bh[nt], acc[mt][nt], 0, 0, 0);
            }
        }
    }

    #pragma unroll
    for (int mt = 0; mt < 2; ++mt) {
        #pragma unroll
        for (int nt = 0; nt < 3; ++nt) {
            int col = wn * 48 + nt * 16 + l15;
            #pragma unroll
            for (int reg = 0; reg < 4; ++reg) {
                int row = m0 + wm * 32 + mt * 16 + quad * 4 + reg;
                if (row < N) {
                    float v = acc[mt][nt][reg];
                    if (col < 40) {
                        ylb[(size_t)row * 40 + col] = f2bf(v);
                    } else if (col < 80) {
                        yr40[(size_t)row * 40 + (col - 40)] = v + b2[col - 40];
                    }
                }
            }
        }
    }
}

// ------- agg40 + pool: out[n] = mean_e ylb[src_e] + yr40[n];
//         gsum[g] += out[n]/cnt(g)  (per-block run-length reduced) ----------
__global__ __launch_bounds__(256) void agg40_pool(
        const unsigned short* __restrict__ ylb, const float* __restrict__ yr40,
        const int* __restrict__ rowptr, const int* __restrict__ csr_src,
        const int* __restrict__ batch, const int* __restrict__ gstart,
        float* __restrict__ out, float* __restrict__ gsum, int N) {
    const int w = (blockIdx.x * blockDim.x + threadIdx.x) >> 6;
    const int lane = threadIdx.x & 63;
    const int wv = threadIdx.x >> 6;
    __shared__ float sh[4][40];
    __shared__ int sg[4];
    __shared__ float sinv[4];

    float val = 0.f;
    const bool valid = (w < N) && (lane < 40);
    if (valid) {
        int s = rowptr[w], e = rowptr[w + 1];
        float acc = 0.f;
        int i = s;
        for (; i + 3 < e; i += 4) {
            int s0 = csr_src[i], s1 = csr_src[i + 1], s2 = csr_src[i + 2], s3 = csr_src[i + 3];
            float v0 = bf2f((short)ylb[(size_t)s0 * 40 + lane]);
            float v1 = bf2f((short)ylb[(size_t)s1 * 40 + lane]);
            float v2 = bf2f((short)ylb[(size_t)s2 * 40 + lane]);
            float v3 = bf2f((short)ylb[(size_t)s3 * 40 + lane]);
            acc += (v0 + v1) + (v2 + v3);
        }
        for (; i < e; ++i) acc += bf2f((short)ylb[(size_t)csr_src[i] * 40 + lane]);
        float inv = 1.0f / fmaxf((float)(e - s), 1.0f);
        val = acc * inv + yr40[(size_t)w * 40 + lane];
        out[(size_t)w * 40 + lane] = val;
        sh[wv][lane] = val;
    }
    if (lane == 0) {
        if (w < N) {
            int g = batch[w];
            sg[wv] = g;
            sinv[wv] = 1.0f / fmaxf((float)(gstart[g + 1] - gstart[g]), 1.0f);
        } else {
            sg[wv] = -1;
        }
    }
    __syncthreads();
    // wave 0 flushes: batch is sorted -> typically one graph per block
    if (wv == 0 && lane < 40) {
        int cur = -1;
        float accum = 0.f;
        #pragma unroll
        for (int k = 0; k < 4; ++k) {
            int gk = sg[k];
            if (gk < 0) continue;
            float c = sh[k][lane] * sinv[k];
            if (gk == cur) {
                accum += c;
            } else {
                if (cur >= 0) atomicAdd(&gsum[cur * 40 + lane], accum);
                cur = gk;
                accum = c;
            }
        }
        if (cur >= 0) atomicAdd(&gsum[cur * 40 + lane], accum);
    }
}

extern "C" void kernel_launch(void* const* d_in, const int* in_sizes, int n_in,
                              void* d_out, int out_size, void* d_ws, size_t ws_size,
                              hipStream_t stream) {
    const float* x    = (const float*)d_in[0];
    const int*   ei   = (const int*)d_in[1];
    const int*   batch= (const int*)d_in[2];
    const float* Wl0  = (const float*)d_in[3];
    const float* bl0  = (const float*)d_in[4];
    const float* Wr0  = (const float*)d_in[5];
    const float* Wl1  = (const float*)d_in[6];
    const float* bl1  = (const float*)d_in[7];
    const float* Wr1  = (const float*)d_in[8];
    const float* Wl2  = (const float*)d_in[9];
    const float* bl2  = (const float*)d_in[10];
    const float* Wr2  = (const float*)d_in[11];

    const int N = in_sizes[0] / K_DIM;       // 50000
    const int E = in_sizes[1] / 2;           // 600000
    const int* src = ei;
    const int* dst = ei + E;

    float* out = (float*)d_out;              // h3 [N,40] then g [128,40]
    float* gsum = out + (size_t)N * 40;

    char* w = (char*)d_ws;
    auto alloc = [&](size_t bytes) {
        char* p = w;
        w += (bytes + 255) & ~(size_t)255;
        return p;
    };
    const size_t PL = (size_t)N * K_DIM * 2;  // one bf16 plane = 12.8 MB
    short* aggb  = (short*)alloc(PL);
    short* xb    = (short*)alloc(PL);
    short* xhi   = (short*)alloc(PL);
    short* xlo   = (short*)alloc(PL);
    short* h1hi  = (short*)alloc(PL);
    short* h1lo  = (short*)alloc(PL);
    short* h2hi  = (short*)alloc(PL);
    short* h2lo  = (short*)alloc(PL);
    short* ylb   = (short*)alloc((size_t)N * 40 * 2);
    float* yr40  = (float*)alloc((size_t)N * 40 * 4);
    int*   rowptr= (int*)alloc((size_t)(N + 1) * 4);
    int*   deg   = (int*)alloc((size_t)N * 4);
    int*   fillp = (int*)alloc((size_t)N * 4);
    int*   csr   = (int*)alloc((size_t)E * 4);
    int*   gstart= (int*)alloc((size_t)(N_GRAPHS + 1) * 4);
    short* whi   = (short*)alloc(77824 * 2);
    short* wlo   = (short*)alloc(77824 * 2);

    int Nv = N, Ev = E, NBv = (N + 255) / 256;

    // ---- cooperative front-end (replaces init/deg/scan_p1/scan_p23/fill) --
    void* kargs[] = {
        (void*)&Wl0, (void*)&Wr0, (void*)&Wl1, (void*)&Wr1, (void*)&Wl2, (void*)&Wr2,
        (void*)&whi, (void*)&wlo,
        (void*)&x, (void*)&xb, (void*)&xhi, (void*)&xlo,
        (void*)&batch, (void*)&gstart,
        (void*)&src, (void*)&dst,
        (void*)&deg, (void*)&rowptr, (void*)&fillp, (void*)&csr,
        (void*)&gsum,
        (void*)&Nv, (void*)&Ev, (void*)&NBv };
    hipLaunchCooperativeKernel((const void*)frontend, dim3(512), dim3(256),
                               kargs, 0, stream);

    short* hWl0 = whi;          short* lWl0 = wlo;
    short* hWr0 = whi + 16384;  short* lWr0 = wlo + 16384;
    short* hWl1 = whi + 32768;  short* lWl1 = wlo + 32768;
    short* hWr1 = whi + 49152;  short* lWr1 = wlo + 49152;
    short* hW2  = whi + 65536;  short* lW2  = wlo + 65536;

    const int aggGrid  = (N * 64 + 255) / 256;   // 12500
    const int gemmGrid = (N + 63) / 64;          // 782

    // layer 0
    agg_bf16<<<aggGrid, 256, 0, stream>>>((const unsigned short*)xb, rowptr, csr, aggb, N);
    sage_mfma<<<gemmGrid, 256, 0, stream>>>(
        aggb, xhi, xlo, hWl0, lWl0, hWr0, lWr0, bl0, h1hi, h1lo, N);
    // layer 1 (h1hi doubles as the gather table: h1 >= 0)
    agg_bf16<<<aggGrid, 256, 0, stream>>>((const unsigned short*)h1hi, rowptr, csr, aggb, N);
    sage_mfma<<<gemmGrid, 256, 0, stream>>>(
        aggb, h1hi, h1lo, hWl1, lWl1, hWr1, lWr1, bl1, h2hi, h2lo, N);
    // layer 2
    gemm80<<<gemmGrid, 256, 0, stream>>>(h2hi, h2lo, hW2, lW2, bl2, ylb, yr40, N);
    agg40_pool<<<aggGrid, 256, 0, stream>>>((const unsigned short*)ylb, yr40,
                                            rowptr, csr, batch, gstart, out, gsum, N);
}

// Round 2
// 336.528 us; speedup vs baseline: 1.6480x; 1.6480x over previous
//
#include <hip/hip_runtime.h>
#include <hip/hip_bf16.h>

// ---------------------------------------------------------------------------
// GraphSAGE 3-layer + global mean pool, fp32 in/out.
//   layer: agg = mean_{e:dst=n} relu(h[src_e]);  h' = agg@Wl^T + bl + h@Wr^T
// R1-R14 history: 810 -> 336us (split kernels, bf16 MFMA hi/lo, bf16 gather).
// R15: cooperative fused front-end REGRESSED badly (268us frontend alone:
//   coop launch caps occupancy at 8 waves/CU for ALL phases -> xconv ran at
//   400 GB/s; grid.sync spin; O(NB^2) scan re-sum). REVERTED.
// R16: split front-end restored (R14 form). KEPT from R15 (both passed,
//   effects masked by frontend):
//   (b) sage_mfma single merged K-loop: 8 barriers instead of 16,
//       40 MFMAs per barrier-pair (same product set).
//   (c) agg40+pool fused via per-block run-length atomics (batch sorted);
//       gsum zeroed in init_kernel (d_out is poisoned by harness).
//   11 dispatches. Predict ~325us.
// ---------------------------------------------------------------------------

#define NODES 50000
#define K_DIM 128
#define N_GRAPHS 128

typedef __attribute__((ext_vector_type(8))) short short8;
typedef __attribute__((ext_vector_type(4))) short short4v;
typedef __attribute__((ext_vector_type(4))) float f32x4;

__device__ inline short f2bf(float f) {
    unsigned u = __builtin_bit_cast(unsigned, f);
    u += 0x7FFFu + ((u >> 16) & 1u);          // RNE
    return (short)(u >> 16);
}
__device__ inline float bf2f(short h) {
    unsigned u = ((unsigned)(unsigned short)h) << 16;
    return __builtin_bit_cast(float, u);
}
__device__ inline float blo(unsigned u) { return __builtin_bit_cast(float, u << 16); }
__device__ inline float bhi(unsigned u) { return __builtin_bit_cast(float, u & 0xFFFF0000u); }
// pack: bits[15:0]=hi bf16, bits[31:16]=lo bf16
__device__ inline unsigned hilo_pack(float f) {
    short h = f2bf(f);
    short l = f2bf(f - bf2f(h));
    return ((unsigned)(unsigned short)h) | (((unsigned)(unsigned short)l) << 16);
}

// ------ init: zero deg+gsum + wconv + gstart + xb=bf16(relu(x)) + xhi/xlo --
__global__ void init_kernel(const float* __restrict__ w0, const float* __restrict__ w1,
                            const float* __restrict__ w2, const float* __restrict__ w3,
                            const float* __restrict__ w4, const float* __restrict__ w5,
                            short* __restrict__ whi, short* __restrict__ wlo,
                            int* __restrict__ deg, const int* __restrict__ batch,
                            int* __restrict__ gstart,
                            const float* __restrict__ x, short* __restrict__ xb,
                            short* __restrict__ xhi, short* __restrict__ xlo,
                            float* __restrict__ gsum, int N) {
    int idx = blockIdx.x * 256 + threadIdx.x;
    if (idx < N * (K_DIM / 4)) {
        float4 v = reinterpret_cast<const float4*>(x)[idx];
        unsigned px = hilo_pack(v.x), py = hilo_pack(v.y);
        unsigned pz = hilo_pack(v.z), pw = hilo_pack(v.w);
        short4v b, hh, ll;
        b[0] = f2bf(fmaxf(v.x, 0.f)); hh[0] = (short)(px & 0xFFFFu); ll[0] = (short)(px >> 16);
        b[1] = f2bf(fmaxf(v.y, 0.f)); hh[1] = (short)(py & 0xFFFFu); ll[1] = (short)(py >> 16);
        b[2] = f2bf(fmaxf(v.z, 0.f)); hh[2] = (short)(pz & 0xFFFFu); ll[2] = (short)(pz >> 16);
        b[3] = f2bf(fmaxf(v.w, 0.f)); hh[3] = (short)(pw & 0xFFFFu); ll[3] = (short)(pw >> 16);
        *reinterpret_cast<short4v*>(&xb [idx * 4]) = b;
        *reinterpret_cast<short4v*>(&xhi[idx * 4]) = hh;
        *reinterpret_cast<short4v*>(&xlo[idx * 4]) = ll;
    }
    if (idx < N) deg[idx] = 0;
    if (idx < N_GRAPHS * 40) gsum[idx] = 0.f;
    const int TOT = 4 * 16384 + 96 * 128;   // 77824
    if (idx < TOT) {
        float v;
        if (idx < 65536) {
            int m = idx >> 14, e = idx & 16383;
            const float* W = (m == 0) ? w0 : (m == 1) ? w1 : (m == 2) ? w2 : w3;
            v = W[e];
        } else {
            int i2 = idx - 65536;
            int row = i2 >> 7, col = i2 & 127;
            if (row < 40)      v = w4[row * 128 + col];
            else if (row < 80) v = w5[(row - 40) * 128 + col];
            else               v = 0.f;
        }
        unsigned p = hilo_pack(v);
        whi[idx] = (short)(p & 0xFFFFu);
        wlo[idx] = (short)(p >> 16);
    }
    if (idx <= N_GRAPHS) {
        int g = idx;
        int lo = 0, hi = N;
        while (lo < hi) {
            int mid = (lo + hi) >> 1;
            if (batch[mid] < g) lo = mid + 1; else hi = mid;
        }
        gstart[g] = lo;
    }
}

// ---------------- CSR build ----------------
__global__ void deg_kernel(const int* __restrict__ dst, int* __restrict__ deg, int E) {
    int e = blockIdx.x * blockDim.x + threadIdx.x;
    if (e < E) atomicAdd(&deg[dst[e]], 1);
}

__global__ void scan_p1(const int* __restrict__ deg, int* __restrict__ bsum, int N) {
    int i = blockIdx.x * 256 + threadIdx.x;
    int v = (i < N) ? deg[i] : 0;
    #pragma unroll
    for (int off = 32; off > 0; off >>= 1) v += __shfl_down(v, off, 64);
    __shared__ int ws[4];
    int lane = threadIdx.x & 63, wv = threadIdx.x >> 6;
    if (lane == 0) ws[wv] = v;
    __syncthreads();
    if (threadIdx.x == 0) bsum[blockIdx.x] = ws[0] + ws[1] + ws[2] + ws[3];
}

// merged p2+p3: each block locally exclusive-scans bsum, then writes its chunk
__global__ void scan_p23(const int* __restrict__ deg, const int* __restrict__ bsum,
                         int* __restrict__ rowptr, int* __restrict__ fillpos,
                         int N, int NB) {
    const int tid = threadIdx.x, lane = tid & 63, wv = tid >> 6;
    __shared__ int ws[4];
    __shared__ int sboff[256];
    {
        int v = (tid < NB) ? bsum[tid] : 0;
        int incl = v;
        #pragma unroll
        for (int off = 1; off < 64; off <<= 1) {
            int t = __shfl_up(incl, off, 64);
            if (lane >= off) incl += t;
        }
        if (lane == 63) ws[wv] = incl;
        __syncthreads();
        int add = 0;
        for (int k = 0; k < wv; ++k) add += ws[k];
        sboff[tid] = incl + add - v;
        __syncthreads();
    }
    const int boff = sboff[blockIdx.x];
    int i = blockIdx.x * 256 + tid;
    int v = (i < N) ? deg[i] : 0;
    int incl = v;
    #pragma unroll
    for (int off = 1; off < 64; off <<= 1) {
        int t = __shfl_up(incl, off, 64);
        if (lane >= off) incl += t;
    }
    __shared__ int ws2[4];
    if (lane == 63) ws2[wv] = incl;
    __syncthreads();
    int add = 0;
    for (int k = 0; k < wv; ++k) add += ws2[k];
    int excl = boff + incl + add - v;
    if (i < N) { rowptr[i] = excl; fillpos[i] = excl; }
    if (i == N) rowptr[N] = excl;
}

__global__ void fill_kernel(const int* __restrict__ src, const int* __restrict__ dst,
                            int* __restrict__ fillpos, int* __restrict__ csr_src, int E) {
    int e = blockIdx.x * blockDim.x + threadIdx.x;
    if (e < E) {
        int p = atomicAdd(&fillpos[dst[e]], 1);
        csr_src[p] = src[e];
    }
}

// ------- aggregation from bf16 table (128-dim) -> bf16 mean ----------------
__global__ void agg_bf16(const unsigned short* __restrict__ hb,
                         const int* __restrict__ rowptr,
                         const int* __restrict__ csr_src,
                         short* __restrict__ aggb, int N) {
    int w = (blockIdx.x * blockDim.x + threadIdx.x) >> 6;
    if (w >= N) return;
    int lane = threadIdx.x & 63;
    int half = lane >> 5, l32 = lane & 31;
    int s = rowptr[w], e = rowptr[w + 1];
    float4 acc = make_float4(0.f, 0.f, 0.f, 0.f);
    int i = s + half;
    for (; i + 6 < e; i += 8) {
        int s0 = csr_src[i], s1 = csr_src[i + 2], s2 = csr_src[i + 4], s3 = csr_src[i + 6];
        uint2 v0 = reinterpret_cast<const uint2*>(hb + (size_t)s0 * K_DIM)[l32];
        uint2 v1 = reinterpret_cast<const uint2*>(hb + (size_t)s1 * K_DIM)[l32];
        uint2 v2 = reinterpret_cast<const uint2*>(hb + (size_t)s2 * K_DIM)[l32];
        uint2 v3 = reinterpret_cast<const uint2*>(hb + (size_t)s3 * K_DIM)[l32];
        acc.x += (blo(v0.x) + blo(v1.x)) + (blo(v2.x) + blo(v3.x));
        acc.y += (bhi(v0.x) + bhi(v1.x)) + (bhi(v2.x) + bhi(v3.x));
        acc.z += (blo(v0.y) + blo(v1.y)) + (blo(v2.y) + blo(v3.y));
        acc.w += (bhi(v0.y) + bhi(v1.y)) + (bhi(v2.y) + bhi(v3.y));
    }
    for (; i < e; i += 2) {
        int s0 = csr_src[i];
        uint2 v0 = reinterpret_cast<const uint2*>(hb + (size_t)s0 * K_DIM)[l32];
        acc.x += blo(v0.x); acc.y += bhi(v0.x);
        acc.z += blo(v0.y); acc.w += bhi(v0.y);
    }
    acc.x += __shfl_xor(acc.x, 32, 64);
    acc.y += __shfl_xor(acc.y, 32, 64);
    acc.z += __shfl_xor(acc.z, 32, 64);
    acc.w += __shfl_xor(acc.w, 32, 64);
    if (half == 0) {
        float inv = 1.0f / fmaxf((float)(e - s), 1.0f);
        short4v b;
        b[0] = f2bf(acc.x * inv);
        b[1] = f2bf(acc.y * inv);
        b[2] = f2bf(acc.z * inv);
        b[3] = f2bf(acc.w * inv);
        *reinterpret_cast<short4v*>(&aggb[(size_t)w * K_DIM + l32 * 4]) = b;
    }
}

// --------- MFMA layer GEMM: out = aggb@Wl^T + bl + H@Wr^T, relu ------------
// Merged K-loop: 8 barriers, 40 MFMAs per barrier-pair.
__global__ __launch_bounds__(256) void sage_mfma(
        const short* __restrict__ Ab_in,
        const short* __restrict__ Hhi_in, const short* __restrict__ Hlo_in,
        const short* __restrict__ Bhl, const short* __restrict__ Bll,
        const short* __restrict__ Bhr, const short* __restrict__ Blr,
        const float* __restrict__ bl,
        short* __restrict__ outHi, short* __restrict__ outLo, int N) {
    constexpr int BM = 64;
    constexpr int LSTR = 40;
    const int tid = threadIdx.x;
    const int lane = tid & 63;
    const int wave = tid >> 6;
    const int l15 = lane & 15;
    const int quad = lane >> 4;
    const int m0 = blockIdx.x * BM;
    const int srow = tid >> 2, sc8 = tid & 3;

    __shared__ __align__(16) short Ab [BM * LSTR];
    __shared__ __align__(16) short Ahi[BM * LSTR];
    __shared__ __align__(16) short Alo[BM * LSTR];

    f32x4 acc[4][2];
    #pragma unroll
    for (int i = 0; i < 4; ++i)
        #pragma unroll
        for (int j = 0; j < 2; ++j) acc[i][j] = (f32x4){0.f, 0.f, 0.f, 0.f};

    const short8 zero8 = (short8){0, 0, 0, 0, 0, 0, 0, 0};
    const int sm = m0 + srow;

    for (int k0 = 0; k0 < K_DIM; k0 += 32) {
        __syncthreads();
        {
            short8 va = zero8, vh = zero8, vl = zero8;
            if (sm < N) {
                va = *reinterpret_cast<const short8*>(Ab_in  + (size_t)sm * K_DIM + k0 + sc8 * 8);
                vh = *reinterpret_cast<const short8*>(Hhi_in + (size_t)sm * K_DIM + k0 + sc8 * 8);
                vl = *reinterpret_cast<const short8*>(Hlo_in + (size_t)sm * K_DIM + k0 + sc8 * 8);
            }
            *reinterpret_cast<short8*>(&Ab [srow * LSTR + sc8 * 8]) = va;
            *reinterpret_cast<short8*>(&Ahi[srow * LSTR + sc8 * 8]) = vh;
            *reinterpret_cast<short8*>(&Alo[srow * LSTR + sc8 * 8]) = vl;
        }
        short8 bhl_[2], bll_[2], bhr_[2], blr_[2];
        #pragma unroll
        for (int nt = 0; nt < 2; ++nt) {
            int n = wave * 32 + nt * 16 + l15;
            size_t off = (size_t)n * K_DIM + k0 + quad * 8;
            bhl_[nt] = *reinterpret_cast<const short8*>(Bhl + off);
            bll_[nt] = *reinterpret_cast<const short8*>(Bll + off);
            bhr_[nt] = *reinterpret_cast<const short8*>(Bhr + off);
            blr_[nt] = *reinterpret_cast<const short8*>(Blr + off);
        }
        __syncthreads();
        #pragma unroll
        for (int mt = 0; mt < 4; ++mt) {
            int row = mt * 16 + l15;
            short8 ab = *reinterpret_cast<const short8*>(&Ab [row * LSTR + quad * 8]);
            short8 ah = *reinterpret_cast<const short8*>(&Ahi[row * LSTR + quad * 8]);
            short8 ao = *reinterpret_cast<const short8*>(&Alo[row * LSTR + quad * 8]);
            #pragma unroll
            for (int nt = 0; nt < 2; ++nt) {
                acc[mt][nt] = __builtin_amdgcn_mfma_f32_16x16x32_bf16(ab, bhl_[nt], acc[mt][nt], 0, 0, 0);
                acc[mt][nt] = __builtin_amdgcn_mfma_f32_16x16x32_bf16(ab, bll_[nt], acc[mt][nt], 0, 0, 0);
                acc[mt][nt] = __builtin_amdgcn_mfma_f32_16x16x32_bf16(ah, bhr_[nt], acc[mt][nt], 0, 0, 0);
                acc[mt][nt] = __builtin_amdgcn_mfma_f32_16x16x32_bf16(ah, blr_[nt], acc[mt][nt], 0, 0, 0);
                acc[mt][nt] = __builtin_amdgcn_mfma_f32_16x16x32_bf16(ao, bhr_[nt], acc[mt][nt], 0, 0, 0);
            }
        }
    }

    // ---- epilogue: relu(acc + bias) -> hi/lo planes ----
    #pragma unroll
    for (int mt = 0; mt < 4; ++mt) {
        #pragma unroll
        for (int nt = 0; nt < 2; ++nt) {
            int col = wave * 32 + nt * 16 + l15;
            float b = bl[col];
            #pragma unroll
            for (int reg = 0; reg < 4; ++reg) {
                int row = m0 + mt * 16 + quad * 4 + reg;
                if (row < N) {
                    float v = fmaxf(acc[mt][nt][reg] + b, 0.f);
                    unsigned p = hilo_pack(v);
                    outHi[(size_t)row * K_DIM + col] = (short)(p & 0xFFFFu);
                    outLo[(size_t)row * K_DIM + col] = (short)(p >> 16);
                }
            }
        }
    }
}

// ------ layer-2 GEMM: ylb = bf16(h2@Wl2^T), yr40 = h2@Wr2^T + bl2 ----------
__global__ __launch_bounds__(256) void gemm80(
        const short* __restrict__ Xhi, const short* __restrict__ Xlo,
        const short* __restrict__ Bh, const short* __restrict__ Bv,
        const float* __restrict__ b2,
        short* __restrict__ ylb, float* __restrict__ yr40, int N) {
    constexpr int BM = 64;
    constexpr int LSTR = 40;
    const int tid = threadIdx.x;
    const int lane = tid & 63;
    const int wave = tid >> 6;
    const int wm = wave & 1;
    const int wn = wave >> 1;
    const int l15 = lane & 15;
    const int quad = lane >> 4;
    const int m0 = blockIdx.x * BM;
    const int srow = tid >> 2, sc8 = tid & 3;

    __shared__ __align__(16) short Ahi[BM * LSTR];
    __shared__ __align__(16) short Alo[BM * LSTR];

    f32x4 acc[2][3];
    #pragma unroll
    for (int i = 0; i < 2; ++i)
        #pragma unroll
        for (int j = 0; j < 3; ++j) acc[i][j] = (f32x4){0.f, 0.f, 0.f, 0.f};

    const short8 zero8 = (short8){0, 0, 0, 0, 0, 0, 0, 0};
    const int sm = m0 + srow;

    for (int k0 = 0; k0 < K_DIM; k0 += 32) {
        __syncthreads();
        {
            short8 vh = zero8, vl = zero8;
            if (sm < N) {
                vh = *reinterpret_cast<const short8*>(Xhi + (size_t)sm * K_DIM + k0 + sc8 * 8);
                vl = *reinterpret_cast<const short8*>(Xlo + (size_t)sm * K_DIM + k0 + sc8 * 8);
            }
            *reinterpret_cast<short8*>(&Ahi[srow * LSTR + sc8 * 8]) = vh;
            *reinterpret_cast<short8*>(&Alo[srow * LSTR + sc8 * 8]) = vl;
        }
        short8 bh[3], bo[3];
        #pragma unroll
        for (int nt = 0; nt < 3; ++nt) {
            int n = wn * 48 + nt * 16 + l15;   // < 96
            bh[nt] = *reinterpret_cast<const short8*>(Bh + (size_t)n * K_DIM + k0 + quad * 8);
            bo[nt] = *reinterpret_cast<const short8*>(Bv + (size_t)n * K_DIM + k0 + quad * 8);
        }
        __syncthreads();
        #pragma unroll
        for (int mt = 0; mt < 2; ++mt) {
            int row = wm * 32 + mt * 16 + l15;
            short8 ah = *reinterpret_cast<const short8*>(&Ahi[row * LSTR + quad * 8]);
            short8 ao = *reinterpret_cast<const short8*>(&Alo[row * LSTR + quad * 8]);
            #pragma unroll
            for (int nt = 0; nt < 3; ++nt) {
                acc[mt][nt] = __builtin_amdgcn_mfma_f32_16x16x32_bf16(ah, bh[nt], acc[mt][nt], 0, 0, 0);
                acc[mt][nt] = __builtin_amdgcn_mfma_f32_16x16x32_bf16(ah, bo[nt], acc[mt][nt], 0, 0, 0);
                acc[mt][nt] = __builtin_amdgcn_mfma_f32_16x16x32_bf16(ao, bh[nt], acc[mt][nt], 0, 0, 0);
            }
        }
    }

    #pragma unroll
    for (int mt = 0; mt < 2; ++mt) {
        #pragma unroll
        for (int nt = 0; nt < 3; ++nt) {
            int col = wn * 48 + nt * 16 + l15;
            #pragma unroll
            for (int reg = 0; reg < 4; ++reg) {
                int row = m0 + wm * 32 + mt * 16 + quad * 4 + reg;
                if (row < N) {
                    float v = acc[mt][nt][reg];
                    if (col < 40) {
                        ylb[(size_t)row * 40 + col] = f2bf(v);
                    } else if (col < 80) {
                        yr40[(size_t)row * 40 + (col - 40)] = v + b2[col - 40];
                    }
                }
            }
        }
    }
}

// ------- agg40 + pool: out[n] = mean_e ylb[src_e] + yr40[n];
//         gsum[g] += out[n]/cnt(g)  (per-block run-length reduced) ----------
__global__ __launch_bounds__(256) void agg40_pool(
        const unsigned short* __restrict__ ylb, const float* __restrict__ yr40,
        const int* __restrict__ rowptr, const int* __restrict__ csr_src,
        const int* __restrict__ batch, const int* __restrict__ gstart,
        float* __restrict__ out, float* __restrict__ gsum, int N) {
    const int w = (blockIdx.x * blockDim.x + threadIdx.x) >> 6;
    const int lane = threadIdx.x & 63;
    const int wv = threadIdx.x >> 6;
    __shared__ float sh[4][40];
    __shared__ int sg[4];
    __shared__ float sinv[4];

    float val = 0.f;
    const bool valid = (w < N) && (lane < 40);
    if (valid) {
        int s = rowptr[w], e = rowptr[w + 1];
        float acc = 0.f;
        int i = s;
        for (; i + 3 < e; i += 4) {
            int s0 = csr_src[i], s1 = csr_src[i + 1], s2 = csr_src[i + 2], s3 = csr_src[i + 3];
            float v0 = bf2f((short)ylb[(size_t)s0 * 40 + lane]);
            float v1 = bf2f((short)ylb[(size_t)s1 * 40 + lane]);
            float v2 = bf2f((short)ylb[(size_t)s2 * 40 + lane]);
            float v3 = bf2f((short)ylb[(size_t)s3 * 40 + lane]);
            acc += (v0 + v1) + (v2 + v3);
        }
        for (; i < e; ++i) acc += bf2f((short)ylb[(size_t)csr_src[i] * 40 + lane]);
        float inv = 1.0f / fmaxf((float)(e - s), 1.0f);
        val = acc * inv + yr40[(size_t)w * 40 + lane];
        out[(size_t)w * 40 + lane] = val;
        sh[wv][lane] = val;
    }
    if (lane == 0) {
        if (w < N) {
            int g = batch[w];
            sg[wv] = g;
            sinv[wv] = 1.0f / fmaxf((float)(gstart[g + 1] - gstart[g]), 1.0f);
        } else {
            sg[wv] = -1;
        }
    }
    __syncthreads();
    // wave 0 flushes: batch is sorted -> typically one graph per block
    if (wv == 0 && lane < 40) {
        int cur = -1;
        float accum = 0.f;
        #pragma unroll
        for (int k = 0; k < 4; ++k) {
            int gk = sg[k];
            if (gk < 0) continue;
            float c = sh[k][lane] * sinv[k];
            if (gk == cur) {
                accum += c;
            } else {
                if (cur >= 0) atomicAdd(&gsum[cur * 40 + lane], accum);
                cur = gk;
                accum = c;
            }
        }
        if (cur >= 0) atomicAdd(&gsum[cur * 40 + lane], accum);
    }
}

extern "C" void kernel_launch(void* const* d_in, const int* in_sizes, int n_in,
                              void* d_out, int out_size, void* d_ws, size_t ws_size,
                              hipStream_t stream) {
    const float* x    = (const float*)d_in[0];
    const int*   ei   = (const int*)d_in[1];
    const int*   batch= (const int*)d_in[2];
    const float* Wl0  = (const float*)d_in[3];
    const float* bl0  = (const float*)d_in[4];
    const float* Wr0  = (const float*)d_in[5];
    const float* Wl1  = (const float*)d_in[6];
    const float* bl1  = (const float*)d_in[7];
    const float* Wr1  = (const float*)d_in[8];
    const float* Wl2  = (const float*)d_in[9];
    const float* bl2  = (const float*)d_in[10];
    const float* Wr2  = (const float*)d_in[11];

    const int N = in_sizes[0] / K_DIM;       // 50000
    const int E = in_sizes[1] / 2;           // 600000
    const int* src = ei;
    const int* dst = ei + E;

    float* out = (float*)d_out;              // h3 [N,40] then g [128,40]
    float* gsum = out + (size_t)N * 40;

    char* w = (char*)d_ws;
    auto alloc = [&](size_t bytes) {
        char* p = w;
        w += (bytes + 255) & ~(size_t)255;
        return p;
    };
    const size_t PL = (size_t)N * K_DIM * 2;  // one bf16 plane = 12.8 MB
    short* aggb  = (short*)alloc(PL);
    short* xb    = (short*)alloc(PL);
    short* xhi   = (short*)alloc(PL);
    short* xlo   = (short*)alloc(PL);
    short* h1hi  = (short*)alloc(PL);
    short* h1lo  = (short*)alloc(PL);
    short* h2hi  = (short*)alloc(PL);
    short* h2lo  = (short*)alloc(PL);
    short* ylb   = (short*)alloc((size_t)N * 40 * 2);
    float* yr40  = (float*)alloc((size_t)N * 40 * 4);
    int*   rowptr= (int*)alloc((size_t)(N + 1) * 4);
    int*   deg   = (int*)alloc((size_t)N * 4);
    int*   fillp = (int*)alloc((size_t)N * 4);
    int*   csr   = (int*)alloc((size_t)E * 4);
    int*   bsum  = (int*)alloc(256 * 4);
    int*   gstart= (int*)alloc((size_t)(N_GRAPHS + 1) * 4);
    short* whi   = (short*)alloc(77824 * 2);
    short* wlo   = (short*)alloc(77824 * 2);

    const int NB = (N + 255) / 256;              // 196
    const int initGrid = (N * (K_DIM / 4) + 255) / 256;   // 6250

    init_kernel<<<initGrid, 256, 0, stream>>>(Wl0, Wr0, Wl1, Wr1, Wl2, Wr2,
                                              whi, wlo, deg, batch, gstart,
                                              x, xb, xhi, xlo, gsum, N);
    deg_kernel<<<(E + 255) / 256, 256, 0, stream>>>(dst, deg, E);
    scan_p1<<<NB, 256, 0, stream>>>(deg, bsum, N);
    scan_p23<<<NB, 256, 0, stream>>>(deg, bsum, rowptr, fillp, N, NB);
    fill_kernel<<<(E + 255) / 256, 256, 0, stream>>>(src, dst, fillp, csr, E);

    short* hWl0 = whi;          short* lWl0 = wlo;
    short* hWr0 = whi + 16384;  short* lWr0 = wlo + 16384;
    short* hWl1 = whi + 32768;  short* lWl1 = wlo + 32768;
    short* hWr1 = whi + 49152;  short* lWr1 = wlo + 49152;
    short* hW2  = whi + 65536;  short* lW2  = wlo + 65536;

    const int aggGrid  = (N * 64 + 255) / 256;   // 12500
    const int gemmGrid = (N + 63) / 64;          // 782

    // layer 0
    agg_bf16<<<aggGrid, 256, 0, stream>>>((const unsigned short*)xb, rowptr, csr, aggb, N);
    sage_mfma<<<gemmGrid, 256, 0, stream>>>(
        aggb, xhi, xlo, hWl0, lWl0, hWr0, lWr0, bl0, h1hi, h1lo, N);
    // layer 1 (h1hi doubles as the gather table: h1 >= 0)
    agg_bf16<<<aggGrid, 256, 0, stream>>>((const unsigned short*)h1hi, rowptr, csr, aggb, N);
    sage_mfma<<<gemmGrid, 256, 0, stream>>>(
        aggb, h1hi, h1lo, hWl1, lWl1, hWr1, lWr1, bl1, h2hi, h2lo, N);
    // layer 2
    gemm80<<<gemmGrid, 256, 0, stream>>>(h2hi, h2lo, hW2, lW2, bl2, ylb, yr40, N);
    agg40_pool<<<aggGrid, 256, 0, stream>>>((const unsigned short*)ylb, yr40,
                                            rowptr, csr, batch, gstart, out, gsum, N);
}

// Round 4
// 326.850 us; speedup vs baseline: 1.6968x; 1.0296x over previous
//
#include <hip/hip_runtime.h>
#include <hip/hip_bf16.h>

// ---------------------------------------------------------------------------
// GraphSAGE 3-layer + global mean pool, fp32 in/out.
//   layer: agg = mean_{e:dst=n} relu(h[src_e]);  h' = agg@Wl^T + bl + h@Wr^T
// R1-R14 history: 810 -> 336us (split kernels, bf16 MFMA hi/lo, bf16 gather).
// R15: cooperative fused front-end REGRESSED (268us: coop occupancy cap).
// R16: revert to split front-end; kept merged-K mfma + fused agg40_pool.
//   Both NEUTRAL (336.5). New info: agg40_pool = 42.8us top dispatch,
//   11% HBM, 22% VALU -> latency-bound, only 4 outstanding gathers/wave.
// R17: (a) agg40_pool restructured like agg_bf16: half-waves alternate
//       edges, 20 lanes x uint (2 packed bf16 dims) = 80B/edge one
//       instruction, unroll 4/half = 8 outstanding loads/wave.
//      (b) xhi/xlo planes deleted; layer-0 GEMM stages fp32 x directly.
// R18: R17 bench was an infra failure (container acquire, no profile);
//       resubmitting identical code to get the measurement.
// ---------------------------------------------------------------------------

#define NODES 50000
#define K_DIM 128
#define N_GRAPHS 128

typedef __attribute__((ext_vector_type(8))) short short8;
typedef __attribute__((ext_vector_type(4))) short short4v;
typedef __attribute__((ext_vector_type(4))) float f32x4;

__device__ inline short f2bf(float f) {
    unsigned u = __builtin_bit_cast(unsigned, f);
    u += 0x7FFFu + ((u >> 16) & 1u);          // RNE
    return (short)(u >> 16);
}
__device__ inline float bf2f(short h) {
    unsigned u = ((unsigned)(unsigned short)h) << 16;
    return __builtin_bit_cast(float, u);
}
__device__ inline float blo(unsigned u) { return __builtin_bit_cast(float, u << 16); }
__device__ inline float bhi(unsigned u) { return __builtin_bit_cast(float, u & 0xFFFF0000u); }
// pack: bits[15:0]=hi bf16, bits[31:16]=lo bf16
__device__ inline unsigned hilo_pack(float f) {
    short h = f2bf(f);
    short l = f2bf(f - bf2f(h));
    return ((unsigned)(unsigned short)h) | (((unsigned)(unsigned short)l) << 16);
}

// ------ init: zero deg+gsum + wconv + gstart + xb=bf16(relu(x)) ------------
__global__ void init_kernel(const float* __restrict__ w0, const float* __restrict__ w1,
                            const float* __restrict__ w2, const float* __restrict__ w3,
                            const float* __restrict__ w4, const float* __restrict__ w5,
                            short* __restrict__ whi, short* __restrict__ wlo,
                            int* __restrict__ deg, const int* __restrict__ batch,
                            int* __restrict__ gstart,
                            const float* __restrict__ x, short* __restrict__ xb,
                            float* __restrict__ gsum, int N) {
    int idx = blockIdx.x * 256 + threadIdx.x;
    if (idx < N * (K_DIM / 4)) {
        float4 v = reinterpret_cast<const float4*>(x)[idx];
        short4v b;
        b[0] = f2bf(fmaxf(v.x, 0.f));
        b[1] = f2bf(fmaxf(v.y, 0.f));
        b[2] = f2bf(fmaxf(v.z, 0.f));
        b[3] = f2bf(fmaxf(v.w, 0.f));
        *reinterpret_cast<short4v*>(&xb[idx * 4]) = b;
    }
    if (idx < N) deg[idx] = 0;
    if (idx < N_GRAPHS * 40) gsum[idx] = 0.f;
    const int TOT = 4 * 16384 + 96 * 128;   // 77824
    if (idx < TOT) {
        float v;
        if (idx < 65536) {
            int m = idx >> 14, e = idx & 16383;
            const float* W = (m == 0) ? w0 : (m == 1) ? w1 : (m == 2) ? w2 : w3;
            v = W[e];
        } else {
            int i2 = idx - 65536;
            int row = i2 >> 7, col = i2 & 127;
            if (row < 40)      v = w4[row * 128 + col];
            else if (row < 80) v = w5[(row - 40) * 128 + col];
            else               v = 0.f;
        }
        unsigned p = hilo_pack(v);
        whi[idx] = (short)(p & 0xFFFFu);
        wlo[idx] = (short)(p >> 16);
    }
    if (idx <= N_GRAPHS) {
        int g = idx;
        int lo = 0, hi = N;
        while (lo < hi) {
            int mid = (lo + hi) >> 1;
            if (batch[mid] < g) lo = mid + 1; else hi = mid;
        }
        gstart[g] = lo;
    }
}

// ---------------- CSR build ----------------
__global__ void deg_kernel(const int* __restrict__ dst, int* __restrict__ deg, int E) {
    int e = blockIdx.x * blockDim.x + threadIdx.x;
    if (e < E) atomicAdd(&deg[dst[e]], 1);
}

__global__ void scan_p1(const int* __restrict__ deg, int* __restrict__ bsum, int N) {
    int i = blockIdx.x * 256 + threadIdx.x;
    int v = (i < N) ? deg[i] : 0;
    #pragma unroll
    for (int off = 32; off > 0; off >>= 1) v += __shfl_down(v, off, 64);
    __shared__ int ws[4];
    int lane = threadIdx.x & 63, wv = threadIdx.x >> 6;
    if (lane == 0) ws[wv] = v;
    __syncthreads();
    if (threadIdx.x == 0) bsum[blockIdx.x] = ws[0] + ws[1] + ws[2] + ws[3];
}

// merged p2+p3: each block locally exclusive-scans bsum, then writes its chunk
__global__ void scan_p23(const int* __restrict__ deg, const int* __restrict__ bsum,
                         int* __restrict__ rowptr, int* __restrict__ fillpos,
                         int N, int NB) {
    const int tid = threadIdx.x, lane = tid & 63, wv = tid >> 6;
    __shared__ int ws[4];
    __shared__ int sboff[256];
    {
        int v = (tid < NB) ? bsum[tid] : 0;
        int incl = v;
        #pragma unroll
        for (int off = 1; off < 64; off <<= 1) {
            int t = __shfl_up(incl, off, 64);
            if (lane >= off) incl += t;
        }
        if (lane == 63) ws[wv] = incl;
        __syncthreads();
        int add = 0;
        for (int k = 0; k < wv; ++k) add += ws[k];
        sboff[tid] = incl + add - v;
        __syncthreads();
    }
    const int boff = sboff[blockIdx.x];
    int i = blockIdx.x * 256 + tid;
    int v = (i < N) ? deg[i] : 0;
    int incl = v;
    #pragma unroll
    for (int off = 1; off < 64; off <<= 1) {
        int t = __shfl_up(incl, off, 64);
        if (lane >= off) incl += t;
    }
    __shared__ int ws2[4];
    if (lane == 63) ws2[wv] = incl;
    __syncthreads();
    int add = 0;
    for (int k = 0; k < wv; ++k) add += ws2[k];
    int excl = boff + incl + add - v;
    if (i < N) { rowptr[i] = excl; fillpos[i] = excl; }
    if (i == N) rowptr[N] = excl;
}

__global__ void fill_kernel(const int* __restrict__ src, const int* __restrict__ dst,
                            int* __restrict__ fillpos, int* __restrict__ csr_src, int E) {
    int e = blockIdx.x * blockDim.x + threadIdx.x;
    if (e < E) {
        int p = atomicAdd(&fillpos[dst[e]], 1);
        csr_src[p] = src[e];
    }
}

// ------- aggregation from bf16 table (128-dim) -> bf16 mean ----------------
__global__ void agg_bf16(const unsigned short* __restrict__ hb,
                         const int* __restrict__ rowptr,
                         const int* __restrict__ csr_src,
                         short* __restrict__ aggb, int N) {
    int w = (blockIdx.x * blockDim.x + threadIdx.x) >> 6;
    if (w >= N) return;
    int lane = threadIdx.x & 63;
    int half = lane >> 5, l32 = lane & 31;
    int s = rowptr[w], e = rowptr[w + 1];
    float4 acc = make_float4(0.f, 0.f, 0.f, 0.f);
    int i = s + half;
    for (; i + 6 < e; i += 8) {
        int s0 = csr_src[i], s1 = csr_src[i + 2], s2 = csr_src[i + 4], s3 = csr_src[i + 6];
        uint2 v0 = reinterpret_cast<const uint2*>(hb + (size_t)s0 * K_DIM)[l32];
        uint2 v1 = reinterpret_cast<const uint2*>(hb + (size_t)s1 * K_DIM)[l32];
        uint2 v2 = reinterpret_cast<const uint2*>(hb + (size_t)s2 * K_DIM)[l32];
        uint2 v3 = reinterpret_cast<const uint2*>(hb + (size_t)s3 * K_DIM)[l32];
        acc.x += (blo(v0.x) + blo(v1.x)) + (blo(v2.x) + blo(v3.x));
        acc.y += (bhi(v0.x) + bhi(v1.x)) + (bhi(v2.x) + bhi(v3.x));
        acc.z += (blo(v0.y) + blo(v1.y)) + (blo(v2.y) + blo(v3.y));
        acc.w += (bhi(v0.y) + bhi(v1.y)) + (bhi(v2.y) + bhi(v3.y));
    }
    for (; i < e; i += 2) {
        int s0 = csr_src[i];
        uint2 v0 = reinterpret_cast<const uint2*>(hb + (size_t)s0 * K_DIM)[l32];
        acc.x += blo(v0.x); acc.y += bhi(v0.x);
        acc.z += blo(v0.y); acc.w += bhi(v0.y);
    }
    acc.x += __shfl_xor(acc.x, 32, 64);
    acc.y += __shfl_xor(acc.y, 32, 64);
    acc.z += __shfl_xor(acc.z, 32, 64);
    acc.w += __shfl_xor(acc.w, 32, 64);
    if (half == 0) {
        float inv = 1.0f / fmaxf((float)(e - s), 1.0f);
        short4v b;
        b[0] = f2bf(acc.x * inv);
        b[1] = f2bf(acc.y * inv);
        b[2] = f2bf(acc.z * inv);
        b[3] = f2bf(acc.w * inv);
        *reinterpret_cast<short4v*>(&aggb[(size_t)w * K_DIM + l32 * 4]) = b;
    }
}

// --------- MFMA layer GEMM: out = aggb@Wl^T + bl + H@Wr^T, relu ------------
// Merged K-loop: 8 barriers, 40 MFMAs per barrier-pair.
// XF32: H operand staged from fp32 x (hilo_pack in-register) instead of
// pre-materialized hi/lo planes.
template<bool XF32>
__global__ __launch_bounds__(256) void sage_mfma_t(
        const short* __restrict__ Ab_in,
        const short* __restrict__ Hhi_in, const short* __restrict__ Hlo_in,
        const float* __restrict__ Xf,
        const short* __restrict__ Bhl, const short* __restrict__ Bll,
        const short* __restrict__ Bhr, const short* __restrict__ Blr,
        const float* __restrict__ bl,
        short* __restrict__ outHi, short* __restrict__ outLo, int N) {
    constexpr int BM = 64;
    constexpr int LSTR = 40;
    const int tid = threadIdx.x;
    const int lane = tid & 63;
    const int wave = tid >> 6;
    const int l15 = lane & 15;
    const int quad = lane >> 4;
    const int m0 = blockIdx.x * BM;
    const int srow = tid >> 2, sc8 = tid & 3;

    __shared__ __align__(16) short Ab [BM * LSTR];
    __shared__ __align__(16) short Ahi[BM * LSTR];
    __shared__ __align__(16) short Alo[BM * LSTR];

    f32x4 acc[4][2];
    #pragma unroll
    for (int i = 0; i < 4; ++i)
        #pragma unroll
        for (int j = 0; j < 2; ++j) acc[i][j] = (f32x4){0.f, 0.f, 0.f, 0.f};

    const short8 zero8 = (short8){0, 0, 0, 0, 0, 0, 0, 0};
    const int sm = m0 + srow;

    for (int k0 = 0; k0 < K_DIM; k0 += 32) {
        __syncthreads();
        {
            short8 va = zero8, vh = zero8, vl = zero8;
            if (sm < N) {
                va = *reinterpret_cast<const short8*>(Ab_in + (size_t)sm * K_DIM + k0 + sc8 * 8);
                if constexpr (XF32) {
                    const float* xp = Xf + (size_t)sm * K_DIM + k0 + sc8 * 8;
                    float4 f0 = *reinterpret_cast<const float4*>(xp);
                    float4 f1 = *reinterpret_cast<const float4*>(xp + 4);
                    float fv[8] = {f0.x, f0.y, f0.z, f0.w, f1.x, f1.y, f1.z, f1.w};
                    #pragma unroll
                    for (int j = 0; j < 8; ++j) {
                        unsigned p = hilo_pack(fv[j]);
                        vh[j] = (short)(p & 0xFFFFu);
                        vl[j] = (short)(p >> 16);
                    }
                } else {
                    vh = *reinterpret_cast<const short8*>(Hhi_in + (size_t)sm * K_DIM + k0 + sc8 * 8);
                    vl = *reinterpret_cast<const short8*>(Hlo_in + (size_t)sm * K_DIM + k0 + sc8 * 8);
                }
            }
            *reinterpret_cast<short8*>(&Ab [srow * LSTR + sc8 * 8]) = va;
            *reinterpret_cast<short8*>(&Ahi[srow * LSTR + sc8 * 8]) = vh;
            *reinterpret_cast<short8*>(&Alo[srow * LSTR + sc8 * 8]) = vl;
        }
        short8 bhl_[2], bll_[2], bhr_[2], blr_[2];
        #pragma unroll
        for (int nt = 0; nt < 2; ++nt) {
            int n = wave * 32 + nt * 16 + l15;
            size_t off = (size_t)n * K_DIM + k0 + quad * 8;
            bhl_[nt] = *reinterpret_cast<const short8*>(Bhl + off);
            bll_[nt] = *reinterpret_cast<const short8*>(Bll + off);
            bhr_[nt] = *reinterpret_cast<const short8*>(Bhr + off);
            blr_[nt] = *reinterpret_cast<const short8*>(Blr + off);
        }
        __syncthreads();
        #pragma unroll
        for (int mt = 0; mt < 4; ++mt) {
            int row = mt * 16 + l15;
            short8 ab = *reinterpret_cast<const short8*>(&Ab [row * LSTR + quad * 8]);
            short8 ah = *reinterpret_cast<const short8*>(&Ahi[row * LSTR + quad * 8]);
            short8 ao = *reinterpret_cast<const short8*>(&Alo[row * LSTR + quad * 8]);
            #pragma unroll
            for (int nt = 0; nt < 2; ++nt) {
                acc[mt][nt] = __builtin_amdgcn_mfma_f32_16x16x32_bf16(ab, bhl_[nt], acc[mt][nt], 0, 0, 0);
                acc[mt][nt] = __builtin_amdgcn_mfma_f32_16x16x32_bf16(ab, bll_[nt], acc[mt][nt], 0, 0, 0);
                acc[mt][nt] = __builtin_amdgcn_mfma_f32_16x16x32_bf16(ah, bhr_[nt], acc[mt][nt], 0, 0, 0);
                acc[mt][nt] = __builtin_amdgcn_mfma_f32_16x16x32_bf16(ah, blr_[nt], acc[mt][nt], 0, 0, 0);
                acc[mt][nt] = __builtin_amdgcn_mfma_f32_16x16x32_bf16(ao, bhr_[nt], acc[mt][nt], 0, 0, 0);
            }
        }
    }

    // ---- epilogue: relu(acc + bias) -> hi/lo planes ----
    #pragma unroll
    for (int mt = 0; mt < 4; ++mt) {
        #pragma unroll
        for (int nt = 0; nt < 2; ++nt) {
            int col = wave * 32 + nt * 16 + l15;
            float b = bl[col];
            #pragma unroll
            for (int reg = 0; reg < 4; ++reg) {
                int row = m0 + mt * 16 + quad * 4 + reg;
                if (row < N) {
                    float v = fmaxf(acc[mt][nt][reg] + b, 0.f);
                    unsigned p = hilo_pack(v);
                    outHi[(size_t)row * K_DIM + col] = (short)(p & 0xFFFFu);
                    outLo[(size_t)row * K_DIM + col] = (short)(p >> 16);
                }
            }
        }
    }
}

// ------ layer-2 GEMM: ylb = bf16(h2@Wl2^T), yr40 = h2@Wr2^T + bl2 ----------
__global__ __launch_bounds__(256) void gemm80(
        const short* __restrict__ Xhi, const short* __restrict__ Xlo,
        const short* __restrict__ Bh, const short* __restrict__ Bv,
        const float* __restrict__ b2,
        short* __restrict__ ylb, float* __restrict__ yr40, int N) {
    constexpr int BM = 64;
    constexpr int LSTR = 40;
    const int tid = threadIdx.x;
    const int lane = tid & 63;
    const int wave = tid >> 6;
    const int wm = wave & 1;
    const int wn = wave >> 1;
    const int l15 = lane & 15;
    const int quad = lane >> 4;
    const int m0 = blockIdx.x * BM;
    const int srow = tid >> 2, sc8 = tid & 3;

    __shared__ __align__(16) short Ahi[BM * LSTR];
    __shared__ __align__(16) short Alo[BM * LSTR];

    f32x4 acc[2][3];
    #pragma unroll
    for (int i = 0; i < 2; ++i)
        #pragma unroll
        for (int j = 0; j < 3; ++j) acc[i][j] = (f32x4){0.f, 0.f, 0.f, 0.f};

    const short8 zero8 = (short8){0, 0, 0, 0, 0, 0, 0, 0};
    const int sm = m0 + srow;

    for (int k0 = 0; k0 < K_DIM; k0 += 32) {
        __syncthreads();
        {
            short8 vh = zero8, vl = zero8;
            if (sm < N) {
                vh = *reinterpret_cast<const short8*>(Xhi + (size_t)sm * K_DIM + k0 + sc8 * 8);
                vl = *reinterpret_cast<const short8*>(Xlo + (size_t)sm * K_DIM + k0 + sc8 * 8);
            }
            *reinterpret_cast<short8*>(&Ahi[srow * LSTR + sc8 * 8]) = vh;
            *reinterpret_cast<short8*>(&Alo[srow * LSTR + sc8 * 8]) = vl;
        }
        short8 bh[3], bo[3];
        #pragma unroll
        for (int nt = 0; nt < 3; ++nt) {
            int n = wn * 48 + nt * 16 + l15;   // < 96
            bh[nt] = *reinterpret_cast<const short8*>(Bh + (size_t)n * K_DIM + k0 + quad * 8);
            bo[nt] = *reinterpret_cast<const short8*>(Bv + (size_t)n * K_DIM + k0 + quad * 8);
        }
        __syncthreads();
        #pragma unroll
        for (int mt = 0; mt < 2; ++mt) {
            int row = wm * 32 + mt * 16 + l15;
            short8 ah = *reinterpret_cast<const short8*>(&Ahi[row * LSTR + quad * 8]);
            short8 ao = *reinterpret_cast<const short8*>(&Alo[row * LSTR + quad * 8]);
            #pragma unroll
            for (int nt = 0; nt < 3; ++nt) {
                acc[mt][nt] = __builtin_amdgcn_mfma_f32_16x16x32_bf16(ah, bh[nt], acc[mt][nt], 0, 0, 0);
                acc[mt][nt] = __builtin_amdgcn_mfma_f32_16x16x32_bf16(ah, bo[nt], acc[mt][nt], 0, 0, 0);
                acc[mt][nt] = __builtin_amdgcn_mfma_f32_16x16x32_bf16(ao, bh[nt], acc[mt][nt], 0, 0, 0);
            }
        }
    }

    #pragma unroll
    for (int mt = 0; mt < 2; ++mt) {
        #pragma unroll
        for (int nt = 0; nt < 3; ++nt) {
            int col = wn * 48 + nt * 16 + l15;
            #pragma unroll
            for (int reg = 0; reg < 4; ++reg) {
                int row = m0 + wm * 32 + mt * 16 + quad * 4 + reg;
                if (row < N) {
                    float v = acc[mt][nt][reg];
                    if (col < 40) {
                        ylb[(size_t)row * 40 + col] = f2bf(v);
                    } else if (col < 80) {
                        yr40[(size_t)row * 40 + (col - 40)] = v + b2[col - 40];
                    }
                }
            }
        }
    }
}

// ------- agg40 + pool: out[n] = mean_e ylb[src_e] + yr40[n];
//         gsum[g] += out[n]/cnt(g).
// R17: half-waves take alternate edges; 20 lanes x uint (2 bf16 dims) =
//   80B/edge one instruction; unroll 4/half = 8 outstanding loads/wave. -----
__global__ __launch_bounds__(256) void agg40_pool(
        const unsigned int* __restrict__ ylbu, const float* __restrict__ yr40,
        const int* __restrict__ rowptr, const int* __restrict__ csr_src,
        const int* __restrict__ batch, const int* __restrict__ gstart,
        float* __restrict__ out, float* __restrict__ gsum, int N) {
    const int w = (blockIdx.x * blockDim.x + threadIdx.x) >> 6;
    const int lane = threadIdx.x & 63;
    const int wv = threadIdx.x >> 6;
    const int half = lane >> 5, l32 = lane & 31;
    __shared__ float sh[4][40];
    __shared__ int sg[4];
    __shared__ float sinv[4];

    if (w < N) {
        int s = rowptr[w], e = rowptr[w + 1];
        float ax = 0.f, ay = 0.f;
        if (l32 < 20) {
            int i = s + half;
            for (; i + 6 < e; i += 8) {
                int s0 = csr_src[i], s1 = csr_src[i + 2], s2 = csr_src[i + 4], s3 = csr_src[i + 6];
                unsigned v0 = ylbu[(size_t)s0 * 20 + l32];
                unsigned v1 = ylbu[(size_t)s1 * 20 + l32];
                unsigned v2 = ylbu[(size_t)s2 * 20 + l32];
                unsigned v3 = ylbu[(size_t)s3 * 20 + l32];
                ax += (blo(v0) + blo(v1)) + (blo(v2) + blo(v3));
                ay += (bhi(v0) + bhi(v1)) + (bhi(v2) + bhi(v3));
            }
            for (; i < e; i += 2) {
                unsigned v0 = ylbu[(size_t)csr_src[i] * 20 + l32];
                ax += blo(v0); ay += bhi(v0);
            }
        }
        ax += __shfl_xor(ax, 32, 64);
        ay += __shfl_xor(ay, 32, 64);
        if (half == 0 && l32 < 20) {
            float inv = 1.0f / fmaxf((float)(e - s), 1.0f);
            float2 yr = *reinterpret_cast<const float2*>(&yr40[(size_t)w * 40 + 2 * l32]);
            float vx = ax * inv + yr.x;
            float vy = ay * inv + yr.y;
            *reinterpret_cast<float2*>(&out[(size_t)w * 40 + 2 * l32]) = make_float2(vx, vy);
            sh[wv][2 * l32]     = vx;
            sh[wv][2 * l32 + 1] = vy;
        }
    }
    if (lane == 0) {
        if (w < N) {
            int g = batch[w];
            sg[wv] = g;
            sinv[wv] = 1.0f / fmaxf((float)(gstart[g + 1] - gstart[g]), 1.0f);
        } else {
            sg[wv] = -1;
        }
    }
    __syncthreads();
    // wave 0 flushes: batch is sorted -> typically one graph per block
    if (wv == 0 && lane < 40) {
        int cur = -1;
        float accum = 0.f;
        #pragma unroll
        for (int k = 0; k < 4; ++k) {
            int gk = sg[k];
            if (gk < 0) continue;
            float c = sh[k][lane] * sinv[k];
            if (gk == cur) {
                accum += c;
            } else {
                if (cur >= 0) atomicAdd(&gsum[cur * 40 + lane], accum);
                cur = gk;
                accum = c;
            }
        }
        if (cur >= 0) atomicAdd(&gsum[cur * 40 + lane], accum);
    }
}

extern "C" void kernel_launch(void* const* d_in, const int* in_sizes, int n_in,
                              void* d_out, int out_size, void* d_ws, size_t ws_size,
                              hipStream_t stream) {
    const float* x    = (const float*)d_in[0];
    const int*   ei   = (const int*)d_in[1];
    const int*   batch= (const int*)d_in[2];
    const float* Wl0  = (const float*)d_in[3];
    const float* bl0  = (const float*)d_in[4];
    const float* Wr0  = (const float*)d_in[5];
    const float* Wl1  = (const float*)d_in[6];
    const float* bl1  = (const float*)d_in[7];
    const float* Wr1  = (const float*)d_in[8];
    const float* Wl2  = (const float*)d_in[9];
    const float* bl2  = (const float*)d_in[10];
    const float* Wr2  = (const float*)d_in[11];

    const int N = in_sizes[0] / K_DIM;       // 50000
    const int E = in_sizes[1] / 2;           // 600000
    const int* src = ei;
    const int* dst = ei + E;

    float* out = (float*)d_out;              // h3 [N,40] then g [128,40]
    float* gsum = out + (size_t)N * 40;

    char* w = (char*)d_ws;
    auto alloc = [&](size_t bytes) {
        char* p = w;
        w += (bytes + 255) & ~(size_t)255;
        return p;
    };
    const size_t PL = (size_t)N * K_DIM * 2;  // one bf16 plane = 12.8 MB
    short* aggb  = (short*)alloc(PL);
    short* xb    = (short*)alloc(PL);
    short* h1hi  = (short*)alloc(PL);
    short* h1lo  = (short*)alloc(PL);
    short* h2hi  = (short*)alloc(PL);
    short* h2lo  = (short*)alloc(PL);
    short* ylb   = (short*)alloc((size_t)N * 40 * 2);
    float* yr40  = (float*)alloc((size_t)N * 40 * 4);
    int*   rowptr= (int*)alloc((size_t)(N + 1) * 4);
    int*   deg   = (int*)alloc((size_t)N * 4);
    int*   fillp = (int*)alloc((size_t)N * 4);
    int*   csr   = (int*)alloc((size_t)E * 4);
    int*   bsum  = (int*)alloc(256 * 4);
    int*   gstart= (int*)alloc((size_t)(N_GRAPHS + 1) * 4);
    short* whi   = (short*)alloc(77824 * 2);
    short* wlo   = (short*)alloc(77824 * 2);

    const int NB = (N + 255) / 256;              // 196
    const int initGrid = (N * (K_DIM / 4) + 255) / 256;   // 6250

    init_kernel<<<initGrid, 256, 0, stream>>>(Wl0, Wr0, Wl1, Wr1, Wl2, Wr2,
                                              whi, wlo, deg, batch, gstart,
                                              x, xb, gsum, N);
    deg_kernel<<<(E + 255) / 256, 256, 0, stream>>>(dst, deg, E);
    scan_p1<<<NB, 256, 0, stream>>>(deg, bsum, N);
    scan_p23<<<NB, 256, 0, stream>>>(deg, bsum, rowptr, fillp, N, NB);
    fill_kernel<<<(E + 255) / 256, 256, 0, stream>>>(src, dst, fillp, csr, E);

    short* hWl0 = whi;          short* lWl0 = wlo;
    short* hWr0 = whi + 16384;  short* lWr0 = wlo + 16384;
    short* hWl1 = whi + 32768;  short* lWl1 = wlo + 32768;
    short* hWr1 = whi + 49152;  short* lWr1 = wlo + 49152;
    short* hW2  = whi + 65536;  short* lW2  = wlo + 65536;

    const int aggGrid  = (N * 64 + 255) / 256;   // 12500
    const int gemmGrid = (N + 63) / 64;          // 782

    // layer 0 (H operand staged from fp32 x directly)
    agg_bf16<<<aggGrid, 256, 0, stream>>>((const unsigned short*)xb, rowptr, csr, aggb, N);
    sage_mfma_t<true><<<gemmGrid, 256, 0, stream>>>(
        aggb, nullptr, nullptr, x, hWl0, lWl0, hWr0, lWr0, bl0, h1hi, h1lo, N);
    // layer 1 (h1hi doubles as the gather table: h1 >= 0)
    agg_bf16<<<aggGrid, 256, 0, stream>>>((const unsigned short*)h1hi, rowptr, csr, aggb, N);
    sage_mfma_t<false><<<gemmGrid, 256, 0, stream>>>(
        aggb, h1hi, h1lo, nullptr, hWl1, lWl1, hWr1, lWr1, bl1, h2hi, h2lo, N);
    // layer 2
    gemm80<<<gemmGrid, 256, 0, stream>>>(h2hi, h2lo, hW2, lW2, bl2, ylb, yr40, N);
    agg40_pool<<<aggGrid, 256, 0, stream>>>((const unsigned int*)ylb, yr40,
                                            rowptr, csr, batch, gstart, out, gsum, N);
}

// Round 5
// 324.956 us; speedup vs baseline: 1.7066x; 1.0058x over previous
//
#include <hip/hip_runtime.h>
#include <hip/hip_bf16.h>

// ---------------------------------------------------------------------------
// GraphSAGE 3-layer + global mean pool, fp32 in/out.
//   layer: agg = mean_{e:dst=n} relu(h[src_e]);  h' = agg@Wl^T + bl + h@Wr^T
// R1-R14 history: 810 -> 336us (split kernels, bf16 MFMA hi/lo, bf16 gather).
// R15: cooperative fused front-end REGRESSED (268us). REVERTED.
// R16: merged-K mfma + fused agg40_pool: NEUTRAL. agg40_pool seen at 42.8us.
// R17/R18: agg40_pool 8-outstanding uint gather + layer0-GEMM stages fp32 x
//   directly: 336.5 -> 326.8us. agg40_pool no longer in top-5.
// R19 (this round):
//   (a) agg_bf16 gather: 16 lanes x uint4 (16B/lane) per edge = 16
//       requests/edge (was 32 x uint2). 4 edge-slots/wave, unroll 2 ->
//       still 8 outstanding. Tests R13's request-rate-limit theory.
//       Predict each agg 27 -> ~17us.
//   (b) scan_p1+scan_p23 merged into csr_offsets (atomic block base;
//       rowptr non-monotone across blocks but ranges disjoint; consumers
//       use end = rowptr[w] + deg[w]). 10 dispatches.
// ---------------------------------------------------------------------------

#define NODES 50000
#define K_DIM 128
#define N_GRAPHS 128

typedef __attribute__((ext_vector_type(8))) short short8;
typedef __attribute__((ext_vector_type(4))) short short4v;
typedef __attribute__((ext_vector_type(4))) float f32x4;

__device__ inline short f2bf(float f) {
    unsigned u = __builtin_bit_cast(unsigned, f);
    u += 0x7FFFu + ((u >> 16) & 1u);          // RNE
    return (short)(u >> 16);
}
__device__ inline float bf2f(short h) {
    unsigned u = ((unsigned)(unsigned short)h) << 16;
    return __builtin_bit_cast(float, u);
}
__device__ inline float blo(unsigned u) { return __builtin_bit_cast(float, u << 16); }
__device__ inline float bhi(unsigned u) { return __builtin_bit_cast(float, u & 0xFFFF0000u); }
// pack: bits[15:0]=hi bf16, bits[31:16]=lo bf16
__device__ inline unsigned hilo_pack(float f) {
    short h = f2bf(f);
    short l = f2bf(f - bf2f(h));
    return ((unsigned)(unsigned short)h) | (((unsigned)(unsigned short)l) << 16);
}

// ------ init: zero deg+gsum+counter + wconv + gstart + xb=bf16(relu(x)) ----
__global__ void init_kernel(const float* __restrict__ w0, const float* __restrict__ w1,
                            const float* __restrict__ w2, const float* __restrict__ w3,
                            const float* __restrict__ w4, const float* __restrict__ w5,
                            short* __restrict__ whi, short* __restrict__ wlo,
                            int* __restrict__ deg, const int* __restrict__ batch,
                            int* __restrict__ gstart, int* __restrict__ counter,
                            const float* __restrict__ x, short* __restrict__ xb,
                            float* __restrict__ gsum, int N) {
    int idx = blockIdx.x * 256 + threadIdx.x;
    if (idx < N * (K_DIM / 4)) {
        float4 v = reinterpret_cast<const float4*>(x)[idx];
        short4v b;
        b[0] = f2bf(fmaxf(v.x, 0.f));
        b[1] = f2bf(fmaxf(v.y, 0.f));
        b[2] = f2bf(fmaxf(v.z, 0.f));
        b[3] = f2bf(fmaxf(v.w, 0.f));
        *reinterpret_cast<short4v*>(&xb[idx * 4]) = b;
    }
    if (idx < N) deg[idx] = 0;
    if (idx < N_GRAPHS * 40) gsum[idx] = 0.f;
    if (idx == 0) *counter = 0;
    const int TOT = 4 * 16384 + 96 * 128;   // 77824
    if (idx < TOT) {
        float v;
        if (idx < 65536) {
            int m = idx >> 14, e = idx & 16383;
            const float* W = (m == 0) ? w0 : (m == 1) ? w1 : (m == 2) ? w2 : w3;
            v = W[e];
        } else {
            int i2 = idx - 65536;
            int row = i2 >> 7, col = i2 & 127;
            if (row < 40)      v = w4[row * 128 + col];
            else if (row < 80) v = w5[(row - 40) * 128 + col];
            else               v = 0.f;
        }
        unsigned p = hilo_pack(v);
        whi[idx] = (short)(p & 0xFFFFu);
        wlo[idx] = (short)(p >> 16);
    }
    if (idx <= N_GRAPHS) {
        int g = idx;
        int lo = 0, hi = N;
        while (lo < hi) {
            int mid = (lo + hi) >> 1;
            if (batch[mid] < g) lo = mid + 1; else hi = mid;
        }
        gstart[g] = lo;
    }
}

// ---------------- CSR build ----------------
__global__ void deg_kernel(const int* __restrict__ dst, int* __restrict__ deg, int E) {
    int e = blockIdx.x * blockDim.x + threadIdx.x;
    if (e < E) atomicAdd(&deg[dst[e]], 1);
}

// single-dispatch offsets: block-local scan + atomic global base.
// rowptr is NOT globally monotone (block bases arrive in arbitrary order),
// but per-node ranges [rowptr[i], rowptr[i]+deg[i]) are disjoint & exact.
__global__ void csr_offsets(const int* __restrict__ deg, int* __restrict__ counter,
                            int* __restrict__ rowptr, int* __restrict__ fillpos, int N) {
    const int tid = threadIdx.x, lane = tid & 63, wv = tid >> 6;
    int i = blockIdx.x * 256 + tid;
    int v = (i < N) ? deg[i] : 0;
    int incl = v;
    #pragma unroll
    for (int off = 1; off < 64; off <<= 1) {
        int t = __shfl_up(incl, off, 64);
        if (lane >= off) incl += t;
    }
    __shared__ int ws[4];
    __shared__ int sbase;
    if (lane == 63) ws[wv] = incl;
    __syncthreads();
    if (tid == 0) sbase = atomicAdd(counter, ws[0] + ws[1] + ws[2] + ws[3]);
    __syncthreads();
    int add = sbase;
    for (int k = 0; k < wv; ++k) add += ws[k];
    int excl = add + incl - v;
    if (i < N) { rowptr[i] = excl; fillpos[i] = excl; }
}

__global__ void fill_kernel(const int* __restrict__ src, const int* __restrict__ dst,
                            int* __restrict__ fillpos, int* __restrict__ csr_src, int E) {
    int e = blockIdx.x * blockDim.x + threadIdx.x;
    if (e < E) {
        int p = atomicAdd(&fillpos[dst[e]], 1);
        csr_src[p] = src[e];
    }
}

// ------- aggregation from bf16 table (128-dim) -> bf16 mean ----------------
// R19: 16 lanes x uint4 per edge (16 requests/edge, was 32). 4 edge-slots
// per wave, unroll 2 -> 8 outstanding 16B loads/wave.
__global__ void agg_bf16(const unsigned short* __restrict__ hb,
                         const int* __restrict__ rowptr, const int* __restrict__ deg,
                         const int* __restrict__ csr_src,
                         short* __restrict__ aggb, int N) {
    int w = (blockIdx.x * blockDim.x + threadIdx.x) >> 6;
    if (w >= N) return;
    int lane = threadIdx.x & 63;
    int slot = lane >> 4, l16 = lane & 15;
    int s = rowptr[w];
    int e = s + deg[w];
    const uint4* T = reinterpret_cast<const uint4*>(hb);   // 16 uint4 per row
    float2 a0 = make_float2(0.f, 0.f), a1 = a0, a2 = a0, a3 = a0;
    int i = s + slot;
    for (; i + 4 < e; i += 8) {
        uint4 va = T[(size_t)csr_src[i] * 16 + l16];
        uint4 vb = T[(size_t)csr_src[i + 4] * 16 + l16];
        a0.x += blo(va.x) + blo(vb.x); a0.y += bhi(va.x) + bhi(vb.x);
        a1.x += blo(va.y) + blo(vb.y); a1.y += bhi(va.y) + bhi(vb.y);
        a2.x += blo(va.z) + blo(vb.z); a2.y += bhi(va.z) + bhi(vb.z);
        a3.x += blo(va.w) + blo(vb.w); a3.y += bhi(va.w) + bhi(vb.w);
    }
    for (; i < e; i += 4) {
        uint4 va = T[(size_t)csr_src[i] * 16 + l16];
        a0.x += blo(va.x); a0.y += bhi(va.x);
        a1.x += blo(va.y); a1.y += bhi(va.y);
        a2.x += blo(va.z); a2.y += bhi(va.z);
        a3.x += blo(va.w); a3.y += bhi(va.w);
    }
    #pragma unroll
    for (int off = 16; off <= 32; off <<= 1) {
        a0.x += __shfl_xor(a0.x, off, 64); a0.y += __shfl_xor(a0.y, off, 64);
        a1.x += __shfl_xor(a1.x, off, 64); a1.y += __shfl_xor(a1.y, off, 64);
        a2.x += __shfl_xor(a2.x, off, 64); a2.y += __shfl_xor(a2.y, off, 64);
        a3.x += __shfl_xor(a3.x, off, 64); a3.y += __shfl_xor(a3.y, off, 64);
    }
    if (slot == 0) {
        float inv = 1.0f / fmaxf((float)(e - s), 1.0f);
        short8 b;
        b[0] = f2bf(a0.x * inv); b[1] = f2bf(a0.y * inv);
        b[2] = f2bf(a1.x * inv); b[3] = f2bf(a1.y * inv);
        b[4] = f2bf(a2.x * inv); b[5] = f2bf(a2.y * inv);
        b[6] = f2bf(a3.x * inv); b[7] = f2bf(a3.y * inv);
        *reinterpret_cast<short8*>(&aggb[(size_t)w * K_DIM + l16 * 8]) = b;
    }
}

// --------- MFMA layer GEMM: out = aggb@Wl^T + bl + H@Wr^T, relu ------------
// Merged K-loop: 8 barriers, 40 MFMAs per barrier-pair.
// XF32: H operand staged from fp32 x (hilo_pack in-register).
template<bool XF32>
__global__ __launch_bounds__(256) void sage_mfma_t(
        const short* __restrict__ Ab_in,
        const short* __restrict__ Hhi_in, const short* __restrict__ Hlo_in,
        const float* __restrict__ Xf,
        const short* __restrict__ Bhl, const short* __restrict__ Bll,
        const short* __restrict__ Bhr, const short* __restrict__ Blr,
        const float* __restrict__ bl,
        short* __restrict__ outHi, short* __restrict__ outLo, int N) {
    constexpr int BM = 64;
    constexpr int LSTR = 40;
    const int tid = threadIdx.x;
    const int lane = tid & 63;
    const int wave = tid >> 6;
    const int l15 = lane & 15;
    const int quad = lane >> 4;
    const int m0 = blockIdx.x * BM;
    const int srow = tid >> 2, sc8 = tid & 3;

    __shared__ __align__(16) short Ab [BM * LSTR];
    __shared__ __align__(16) short Ahi[BM * LSTR];
    __shared__ __align__(16) short Alo[BM * LSTR];

    f32x4 acc[4][2];
    #pragma unroll
    for (int i = 0; i < 4; ++i)
        #pragma unroll
        for (int j = 0; j < 2; ++j) acc[i][j] = (f32x4){0.f, 0.f, 0.f, 0.f};

    const short8 zero8 = (short8){0, 0, 0, 0, 0, 0, 0, 0};
    const int sm = m0 + srow;

    for (int k0 = 0; k0 < K_DIM; k0 += 32) {
        __syncthreads();
        {
            short8 va = zero8, vh = zero8, vl = zero8;
            if (sm < N) {
                va = *reinterpret_cast<const short8*>(Ab_in + (size_t)sm * K_DIM + k0 + sc8 * 8);
                if constexpr (XF32) {
                    const float* xp = Xf + (size_t)sm * K_DIM + k0 + sc8 * 8;
                    float4 f0 = *reinterpret_cast<const float4*>(xp);
                    float4 f1 = *reinterpret_cast<const float4*>(xp + 4);
                    float fv[8] = {f0.x, f0.y, f0.z, f0.w, f1.x, f1.y, f1.z, f1.w};
                    #pragma unroll
                    for (int j = 0; j < 8; ++j) {
                        unsigned p = hilo_pack(fv[j]);
                        vh[j] = (short)(p & 0xFFFFu);
                        vl[j] = (short)(p >> 16);
                    }
                } else {
                    vh = *reinterpret_cast<const short8*>(Hhi_in + (size_t)sm * K_DIM + k0 + sc8 * 8);
                    vl = *reinterpret_cast<const short8*>(Hlo_in + (size_t)sm * K_DIM + k0 + sc8 * 8);
                }
            }
            *reinterpret_cast<short8*>(&Ab [srow * LSTR + sc8 * 8]) = va;
            *reinterpret_cast<short8*>(&Ahi[srow * LSTR + sc8 * 8]) = vh;
            *reinterpret_cast<short8*>(&Alo[srow * LSTR + sc8 * 8]) = vl;
        }
        short8 bhl_[2], bll_[2], bhr_[2], blr_[2];
        #pragma unroll
        for (int nt = 0; nt < 2; ++nt) {
            int n = wave * 32 + nt * 16 + l15;
            size_t off = (size_t)n * K_DIM + k0 + quad * 8;
            bhl_[nt] = *reinterpret_cast<const short8*>(Bhl + off);
            bll_[nt] = *reinterpret_cast<const short8*>(Bll + off);
            bhr_[nt] = *reinterpret_cast<const short8*>(Bhr + off);
            blr_[nt] = *reinterpret_cast<const short8*>(Blr + off);
        }
        __syncthreads();
        #pragma unroll
        for (int mt = 0; mt < 4; ++mt) {
            int row = mt * 16 + l15;
            short8 ab = *reinterpret_cast<const short8*>(&Ab [row * LSTR + quad * 8]);
            short8 ah = *reinterpret_cast<const short8*>(&Ahi[row * LSTR + quad * 8]);
            short8 ao = *reinterpret_cast<const short8*>(&Alo[row * LSTR + quad * 8]);
            #pragma unroll
            for (int nt = 0; nt < 2; ++nt) {
                acc[mt][nt] = __builtin_amdgcn_mfma_f32_16x16x32_bf16(ab, bhl_[nt], acc[mt][nt], 0, 0, 0);
                acc[mt][nt] = __builtin_amdgcn_mfma_f32_16x16x32_bf16(ab, bll_[nt], acc[mt][nt], 0, 0, 0);
                acc[mt][nt] = __builtin_amdgcn_mfma_f32_16x16x32_bf16(ah, bhr_[nt], acc[mt][nt], 0, 0, 0);
                acc[mt][nt] = __builtin_amdgcn_mfma_f32_16x16x32_bf16(ah, blr_[nt], acc[mt][nt], 0, 0, 0);
                acc[mt][nt] = __builtin_amdgcn_mfma_f32_16x16x32_bf16(ao, bhr_[nt], acc[mt][nt], 0, 0, 0);
            }
        }
    }

    // ---- epilogue: relu(acc + bias) -> hi/lo planes ----
    #pragma unroll
    for (int mt = 0; mt < 4; ++mt) {
        #pragma unroll
        for (int nt = 0; nt < 2; ++nt) {
            int col = wave * 32 + nt * 16 + l15;
            float b = bl[col];
            #pragma unroll
            for (int reg = 0; reg < 4; ++reg) {
                int row = m0 + mt * 16 + quad * 4 + reg;
                if (row < N) {
                    float v = fmaxf(acc[mt][nt][reg] + b, 0.f);
                    unsigned p = hilo_pack(v);
                    outHi[(size_t)row * K_DIM + col] = (short)(p & 0xFFFFu);
                    outLo[(size_t)row * K_DIM + col] = (short)(p >> 16);
                }
            }
        }
    }
}

// ------ layer-2 GEMM: ylb = bf16(h2@Wl2^T), yr40 = h2@Wr2^T + bl2 ----------
__global__ __launch_bounds__(256) void gemm80(
        const short* __restrict__ Xhi, const short* __restrict__ Xlo,
        const short* __restrict__ Bh, const short* __restrict__ Bv,
        const float* __restrict__ b2,
        short* __restrict__ ylb, float* __restrict__ yr40, int N) {
    constexpr int BM = 64;
    constexpr int LSTR = 40;
    const int tid = threadIdx.x;
    const int lane = tid & 63;
    const int wave = tid >> 6;
    const int wm = wave & 1;
    const int wn = wave >> 1;
    const int l15 = lane & 15;
    const int quad = lane >> 4;
    const int m0 = blockIdx.x * BM;
    const int srow = tid >> 2, sc8 = tid & 3;

    __shared__ __align__(16) short Ahi[BM * LSTR];
    __shared__ __align__(16) short Alo[BM * LSTR];

    f32x4 acc[2][3];
    #pragma unroll
    for (int i = 0; i < 2; ++i)
        #pragma unroll
        for (int j = 0; j < 3; ++j) acc[i][j] = (f32x4){0.f, 0.f, 0.f, 0.f};

    const short8 zero8 = (short8){0, 0, 0, 0, 0, 0, 0, 0};
    const int sm = m0 + srow;

    for (int k0 = 0; k0 < K_DIM; k0 += 32) {
        __syncthreads();
        {
            short8 vh = zero8, vl = zero8;
            if (sm < N) {
                vh = *reinterpret_cast<const short8*>(Xhi + (size_t)sm * K_DIM + k0 + sc8 * 8);
                vl = *reinterpret_cast<const short8*>(Xlo + (size_t)sm * K_DIM + k0 + sc8 * 8);
            }
            *reinterpret_cast<short8*>(&Ahi[srow * LSTR + sc8 * 8]) = vh;
            *reinterpret_cast<short8*>(&Alo[srow * LSTR + sc8 * 8]) = vl;
        }
        short8 bh[3], bo[3];
        #pragma unroll
        for (int nt = 0; nt < 3; ++nt) {
            int n = wn * 48 + nt * 16 + l15;   // < 96
            bh[nt] = *reinterpret_cast<const short8*>(Bh + (size_t)n * K_DIM + k0 + quad * 8);
            bo[nt] = *reinterpret_cast<const short8*>(Bv + (size_t)n * K_DIM + k0 + quad * 8);
        }
        __syncthreads();
        #pragma unroll
        for (int mt = 0; mt < 2; ++mt) {
            int row = wm * 32 + mt * 16 + l15;
            short8 ah = *reinterpret_cast<const short8*>(&Ahi[row * LSTR + quad * 8]);
            short8 ao = *reinterpret_cast<const short8*>(&Alo[row * LSTR + quad * 8]);
            #pragma unroll
            for (int nt = 0; nt < 3; ++nt) {
                acc[mt][nt] = __builtin_amdgcn_mfma_f32_16x16x32_bf16(ah, bh[nt], acc[mt][nt], 0, 0, 0);
                acc[mt][nt] = __builtin_amdgcn_mfma_f32_16x16x32_bf16(ah, bo[nt], acc[mt][nt], 0, 0, 0);
                acc[mt][nt] = __builtin_amdgcn_mfma_f32_16x16x32_bf16(ao, bh[nt], acc[mt][nt], 0, 0, 0);
            }
        }
    }

    #pragma unroll
    for (int mt = 0; mt < 2; ++mt) {
        #pragma unroll
        for (int nt = 0; nt < 3; ++nt) {
            int col = wn * 48 + nt * 16 + l15;
            #pragma unroll
            for (int reg = 0; reg < 4; ++reg) {
                int row = m0 + wm * 32 + mt * 16 + quad * 4 + reg;
                if (row < N) {
                    float v = acc[mt][nt][reg];
                    if (col < 40) {
                        ylb[(size_t)row * 40 + col] = f2bf(v);
                    } else if (col < 80) {
                        yr40[(size_t)row * 40 + (col - 40)] = v + b2[col - 40];
                    }
                }
            }
        }
    }
}

// ------- agg40 + pool: out[n] = mean_e ylb[src_e] + yr40[n];
//         gsum[g] += out[n]/cnt(g). --------------------------------------
__global__ __launch_bounds__(256) void agg40_pool(
        const unsigned int* __restrict__ ylbu, const float* __restrict__ yr40,
        const int* __restrict__ rowptr, const int* __restrict__ deg,
        const int* __restrict__ csr_src,
        const int* __restrict__ batch, const int* __restrict__ gstart,
        float* __restrict__ out, float* __restrict__ gsum, int N) {
    const int w = (blockIdx.x * blockDim.x + threadIdx.x) >> 6;
    const int lane = threadIdx.x & 63;
    const int wv = threadIdx.x >> 6;
    const int half = lane >> 5, l32 = lane & 31;
    __shared__ float sh[4][40];
    __shared__ int sg[4];
    __shared__ float sinv[4];

    if (w < N) {
        int s = rowptr[w], e = s + deg[w];
        float ax = 0.f, ay = 0.f;
        if (l32 < 20) {
            int i = s + half;
            for (; i + 6 < e; i += 8) {
                int s0 = csr_src[i], s1 = csr_src[i + 2], s2 = csr_src[i + 4], s3 = csr_src[i + 6];
                unsigned v0 = ylbu[(size_t)s0 * 20 + l32];
                unsigned v1 = ylbu[(size_t)s1 * 20 + l32];
                unsigned v2 = ylbu[(size_t)s2 * 20 + l32];
                unsigned v3 = ylbu[(size_t)s3 * 20 + l32];
                ax += (blo(v0) + blo(v1)) + (blo(v2) + blo(v3));
                ay += (bhi(v0) + bhi(v1)) + (bhi(v2) + bhi(v3));
            }
            for (; i < e; i += 2) {
                unsigned v0 = ylbu[(size_t)csr_src[i] * 20 + l32];
                ax += blo(v0); ay += bhi(v0);
            }
        }
        ax += __shfl_xor(ax, 32, 64);
        ay += __shfl_xor(ay, 32, 64);
        if (half == 0 && l32 < 20) {
            float inv = 1.0f / fmaxf((float)(e - s), 1.0f);
            float2 yr = *reinterpret_cast<const float2*>(&yr40[(size_t)w * 40 + 2 * l32]);
            float vx = ax * inv + yr.x;
            float vy = ay * inv + yr.y;
            *reinterpret_cast<float2*>(&out[(size_t)w * 40 + 2 * l32]) = make_float2(vx, vy);
            sh[wv][2 * l32]     = vx;
            sh[wv][2 * l32 + 1] = vy;
        }
    }
    if (lane == 0) {
        if (w < N) {
            int g = batch[w];
            sg[wv] = g;
            sinv[wv] = 1.0f / fmaxf((float)(gstart[g + 1] - gstart[g]), 1.0f);
        } else {
            sg[wv] = -1;
        }
    }
    __syncthreads();
    // wave 0 flushes: batch is sorted -> typically one graph per block
    if (wv == 0 && lane < 40) {
        int cur = -1;
        float accum = 0.f;
        #pragma unroll
        for (int k = 0; k < 4; ++k) {
            int gk = sg[k];
            if (gk < 0) continue;
            float c = sh[k][lane] * sinv[k];
            if (gk == cur) {
                accum += c;
            } else {
                if (cur >= 0) atomicAdd(&gsum[cur * 40 + lane], accum);
                cur = gk;
                accum = c;
            }
        }
        if (cur >= 0) atomicAdd(&gsum[cur * 40 + lane], accum);
    }
}

extern "C" void kernel_launch(void* const* d_in, const int* in_sizes, int n_in,
                              void* d_out, int out_size, void* d_ws, size_t ws_size,
                              hipStream_t stream) {
    const float* x    = (const float*)d_in[0];
    const int*   ei   = (const int*)d_in[1];
    const int*   batch= (const int*)d_in[2];
    const float* Wl0  = (const float*)d_in[3];
    const float* bl0  = (const float*)d_in[4];
    const float* Wr0  = (const float*)d_in[5];
    const float* Wl1  = (const float*)d_in[6];
    const float* bl1  = (const float*)d_in[7];
    const float* Wr1  = (const float*)d_in[8];
    const float* Wl2  = (const float*)d_in[9];
    const float* bl2  = (const float*)d_in[10];
    const float* Wr2  = (const float*)d_in[11];

    const int N = in_sizes[0] / K_DIM;       // 50000
    const int E = in_sizes[1] / 2;           // 600000
    const int* src = ei;
    const int* dst = ei + E;

    float* out = (float*)d_out;              // h3 [N,40] then g [128,40]
    float* gsum = out + (size_t)N * 40;

    char* w = (char*)d_ws;
    auto alloc = [&](size_t bytes) {
        char* p = w;
        w += (bytes + 255) & ~(size_t)255;
        return p;
    };
    const size_t PL = (size_t)N * K_DIM * 2;  // one bf16 plane = 12.8 MB
    short* aggb  = (short*)alloc(PL);
    short* xb    = (short*)alloc(PL);
    short* h1hi  = (short*)alloc(PL);
    short* h1lo  = (short*)alloc(PL);
    short* h2hi  = (short*)alloc(PL);
    short* h2lo  = (short*)alloc(PL);
    short* ylb   = (short*)alloc((size_t)N * 40 * 2);
    float* yr40  = (float*)alloc((size_t)N * 40 * 4);
    int*   rowptr= (int*)alloc((size_t)(N + 1) * 4);
    int*   deg   = (int*)alloc((size_t)N * 4);
    int*   fillp = (int*)alloc((size_t)N * 4);
    int*   csr   = (int*)alloc((size_t)E * 4);
    int*   counter = (int*)alloc(256);
    int*   gstart= (int*)alloc((size_t)(N_GRAPHS + 1) * 4);
    short* whi   = (short*)alloc(77824 * 2);
    short* wlo   = (short*)alloc(77824 * 2);

    const int NB = (N + 255) / 256;              // 196
    const int initGrid = (N * (K_DIM / 4) + 255) / 256;   // 6250

    init_kernel<<<initGrid, 256, 0, stream>>>(Wl0, Wr0, Wl1, Wr1, Wl2, Wr2,
                                              whi, wlo, deg, batch, gstart, counter,
                                              x, xb, gsum, N);
    deg_kernel<<<(E + 255) / 256, 256, 0, stream>>>(dst, deg, E);
    csr_offsets<<<NB, 256, 0, stream>>>(deg, counter, rowptr, fillp, N);
    fill_kernel<<<(E + 255) / 256, 256, 0, stream>>>(src, dst, fillp, csr, E);

    short* hWl0 = whi;          short* lWl0 = wlo;
    short* hWr0 = whi + 16384;  short* lWr0 = wlo + 16384;
    short* hWl1 = whi + 32768;  short* lWl1 = wlo + 32768;
    short* hWr1 = whi + 49152;  short* lWr1 = wlo + 49152;
    short* hW2  = whi + 65536;  short* lW2  = wlo + 65536;

    const int aggGrid  = (N * 64 + 255) / 256;   // 12500
    const int gemmGrid = (N + 63) / 64;          // 782

    // layer 0 (H operand staged from fp32 x directly)
    agg_bf16<<<aggGrid, 256, 0, stream>>>((const unsigned short*)xb, rowptr, deg, csr, aggb, N);
    sage_mfma_t<true><<<gemmGrid, 256, 0, stream>>>(
        aggb, nullptr, nullptr, x, hWl0, lWl0, hWr0, lWr0, bl0, h1hi, h1lo, N);
    // layer 1 (h1hi doubles as the gather table: h1 >= 0)
    agg_bf16<<<aggGrid, 256, 0, stream>>>((const unsigned short*)h1hi, rowptr, deg, csr, aggb, N);
    sage_mfma_t<false><<<gemmGrid, 256, 0, stream>>>(
        aggb, h1hi, h1lo, nullptr, hWl1, lWl1, hWr1, lWr1, bl1, h2hi, h2lo, N);
    // layer 2
    gemm80<<<gemmGrid, 256, 0, stream>>>(h2hi, h2lo, hW2, lW2, bl2, ylb, yr40, N);
    agg40_pool<<<aggGrid, 256, 0, stream>>>((const unsigned int*)ylb, yr40,
                                            rowptr, deg, csr, batch, gstart, out, gsum, N);
}